// Round 1
// baseline (2345.842 us; speedup 1.0000x reference)
//
#include <hip/hip_runtime.h>
#include <hip/hip_bf16.h>

#define S_LEN 2048
#define HDIM  1024
#define NHEAD 16
#define NKVH  4
#define HEADD 64
#define QKV_O 1536   // NKV*(q_per_kv+2)*HD = 4*6*64
#define NEXP  8
#define TOPK  2
#define CAP   640    // ceil(2048*2/8*1.25)
#define TCAP  (NEXP*CAP)
#define FDIM  2048

// ---------------- LayerNorm ----------------
__global__ void ln_kernel(const float* __restrict__ in, const float* __restrict__ w,
                          const float* __restrict__ b, float* __restrict__ out) {
    int row = blockIdx.x;
    const float* x = in + (size_t)row * HDIM;
    float* o = out + (size_t)row * HDIM;
    __shared__ float red[256];
    int tid = threadIdx.x;
    float s = 0.f;
    for (int i = tid; i < HDIM; i += 256) s += x[i];
    red[tid] = s; __syncthreads();
    for (int st = 128; st > 0; st >>= 1) { if (tid < st) red[tid] += red[tid+st]; __syncthreads(); }
    float mu = red[0] / HDIM; __syncthreads();
    float v = 0.f;
    for (int i = tid; i < HDIM; i += 256) { float d = x[i]-mu; v += d*d; }
    red[tid] = v; __syncthreads();
    for (int st = 128; st > 0; st >>= 1) { if (tid < st) red[tid] += red[tid+st]; __syncthreads(); }
    float rstd = rsqrtf(red[0]/HDIM + 1e-5f);
    for (int i = tid; i < HDIM; i += 256) o[i] = (x[i]-mu)*rstd*w[i] + b[i];
}

// ---------------- GEMM: C[M,N] = A[M,K] * (BT ? W[N,K]^T : W[K,N]) ----------------
// EPI: 0 = none, 1 = += R[M,N] (residual), 2 = gelu(tanh approx)
template<bool BT, int EPI>
__global__ __launch_bounds__(256)
void gemm_kernel(const float* __restrict__ A, const float* __restrict__ W,
                 const float* __restrict__ R, float* __restrict__ C,
                 int M, int N, int Kd,
                 long strideA, long strideW, long strideC) {
    __shared__ float As[16][68];
    __shared__ float Bs[16][68];
    int e = blockIdx.z;
    A += (size_t)e * strideA;
    W += (size_t)e * strideW;
    C += (size_t)e * strideC;
    int m0 = blockIdx.y * 64, n0 = blockIdx.x * 64;
    int tid = threadIdx.x;
    int tx = tid & 15, ty = tid >> 4;
    float c[4][4] = {};
    for (int k0 = 0; k0 < Kd; k0 += 16) {
        {
            int idx = tid * 4;
            int m = idx >> 4, kk = idx & 15;
            float4 a = *(const float4*)(A + (size_t)(m0+m)*Kd + k0 + kk);
            As[kk+0][m] = a.x; As[kk+1][m] = a.y; As[kk+2][m] = a.z; As[kk+3][m] = a.w;
        }
        if (BT) {
            int idx = tid * 4;
            int n = idx >> 4, kk = idx & 15;
            float4 b = *(const float4*)(W + (size_t)(n0+n)*Kd + k0 + kk);
            Bs[kk+0][n] = b.x; Bs[kk+1][n] = b.y; Bs[kk+2][n] = b.z; Bs[kk+3][n] = b.w;
        } else {
            int idx = tid * 4;
            int kk = idx >> 6, n = idx & 63;
            float4 b = *(const float4*)(W + (size_t)(k0+kk)*N + n0 + n);
            Bs[kk][n+0] = b.x; Bs[kk][n+1] = b.y; Bs[kk][n+2] = b.z; Bs[kk][n+3] = b.w;
        }
        __syncthreads();
        #pragma unroll
        for (int kk = 0; kk < 16; ++kk) {
            float av[4], bv[4];
            #pragma unroll
            for (int i = 0; i < 4; ++i) av[i] = As[kk][ty*4+i];
            #pragma unroll
            for (int j = 0; j < 4; ++j) bv[j] = Bs[kk][tx*4+j];
            #pragma unroll
            for (int i = 0; i < 4; ++i)
                #pragma unroll
                for (int j = 0; j < 4; ++j)
                    c[i][j] += av[i] * bv[j];
        }
        __syncthreads();
    }
    #pragma unroll
    for (int i = 0; i < 4; ++i) {
        int m = m0 + ty*4 + i;
        #pragma unroll
        for (int j = 0; j < 4; ++j) {
            int n = n0 + tx*4 + j;
            float v = c[i][j];
            if (EPI == 1) v += R[(size_t)m*N + n];
            if (EPI == 2) {
                float t = 0.7978845608028654f * (v + 0.044715f * v*v*v);
                v = 0.5f * v * (1.f + tanhf(t));
            }
            C[(size_t)m*N + n] = v;
        }
    }
}

// ---------------- Attention (flash-style, one block per (q, head)) ----------------
__global__ __launch_bounds__(256)
void attn_kernel(const float* __restrict__ qkv, float* __restrict__ ao) {
    int q = blockIdx.x, h = blockIdx.y;
    int g = h >> 2, qi = h & 3;
    const float* qrow = qkv + (size_t)q*QKV_O + g*384 + qi*64;
    __shared__ float qv[64];
    __shared__ float pbuf[256];
    __shared__ float red[256];
    int tid = threadIdx.x;
    if (tid < 64) qv[tid] = qrow[tid] * 0.125f;   // fold 1/sqrt(64)
    __syncthreads();
    float m = -INFINITY, l = 0.f, acc = 0.f;
    int w = tid >> 6, d = tid & 63;
    int nk = q + 1;
    for (int k0 = 0; k0 < nk; k0 += 256) {
        int kt = k0 + tid;
        float s = -INFINITY;
        if (kt < nk) {
            const float* krow = qkv + (size_t)kt*QKV_O + g*384 + 256;
            float a = 0.f;
            #pragma unroll
            for (int d2 = 0; d2 < 64; d2 += 4) {
                float4 k4 = *(const float4*)(krow + d2);
                a += qv[d2]*k4.x + qv[d2+1]*k4.y + qv[d2+2]*k4.z + qv[d2+3]*k4.w;
            }
            s = a;
        }
        red[tid] = s; __syncthreads();
        for (int st = 128; st > 0; st >>= 1) { if (tid < st) red[tid] = fmaxf(red[tid], red[tid+st]); __syncthreads(); }
        float mn = fmaxf(m, red[0]);
        float corr = __expf(m - mn);             // exp(-inf)=0 on first chunk
        float p = (kt < nk) ? __expf(s - mn) : 0.f;
        __syncthreads();
        red[tid] = p; pbuf[tid] = p; __syncthreads();
        for (int st = 128; st > 0; st >>= 1) { if (tid < st) red[tid] += red[tid+st]; __syncthreads(); }
        l = l * corr + red[0];
        m = mn;
        acc *= corr;
        int kbase = k0 + w*64;
        int jmax = min(64, nk - kbase);
        for (int j = 0; j < jmax; ++j) {
            const float* vrow = qkv + (size_t)(kbase+j)*QKV_O + g*384 + 320;
            acc += pbuf[w*64+j] * vrow[d];
        }
        __syncthreads();
    }
    red[tid] = acc; __syncthreads();
    if (tid < 64) {
        float r = red[tid] + red[tid+64] + red[tid+128] + red[tid+192];
        ao[(size_t)q*HDIM + h*64 + tid] = r / l;
    }
}

// ---------------- Router: f32 logits, top-2, renormalized probs ----------------
__global__ __launch_bounds__(256)
void router_kernel(const float* __restrict__ x, const float* __restrict__ rw,
                   int* __restrict__ expi, float* __restrict__ expp) {
    int t = blockIdx.x, tid = threadIdx.x;
    __shared__ float red[256][8];
    float part[8] = {};
    const float* xr = x + (size_t)t*HDIM;
    for (int i = tid; i < HDIM; i += 256) {
        float xv = xr[i];
        const float* wp = rw + (size_t)i*NEXP;
        #pragma unroll
        for (int e2 = 0; e2 < 8; ++e2) part[e2] += xv * wp[e2];
    }
    #pragma unroll
    for (int e2 = 0; e2 < 8; ++e2) red[tid][e2] = part[e2];
    __syncthreads();
    for (int st = 128; st > 0; st >>= 1) {
        if (tid < st)
            #pragma unroll
            for (int e2 = 0; e2 < 8; ++e2) red[tid][e2] += red[tid+st][e2];
        __syncthreads();
    }
    if (tid == 0) {
        float lg[8];
        #pragma unroll
        for (int e2 = 0; e2 < 8; ++e2) lg[e2] = red[0][e2];
        int i0 = 0;
        for (int e2 = 1; e2 < 8; ++e2) if (lg[e2] > lg[i0]) i0 = e2;
        int i1 = -1;
        for (int e2 = 0; e2 < 8; ++e2) { if (e2 == i0) continue; if (i1 < 0 || lg[e2] > lg[i1]) i1 = e2; }
        float p1 = __expf(lg[i1] - lg[i0]);
        float inv = 1.f / (1.f + p1);
        expi[t*2]   = i0; expi[t*2+1] = i1;
        expp[t*2]   = inv; expp[t*2+1] = p1 * inv;
    }
}

// ---------------- Slot -> destination (stable, capacity-limited) ----------------
__global__ void dst_kernel(const int* __restrict__ expi, int* __restrict__ dst) {
    int s = blockIdx.x * blockDim.x + threadIdx.x;
    if (s >= S_LEN * TOPK) return;
    int e = expi[s];
    int within = 0;
    for (int i = 0; i < s; ++i) within += (expi[i] == e);
    dst[s] = (within < CAP) ? (e * CAP + within) : -1;
}

// ---------------- Scatter tokens into padded [E*cap, H] ----------------
__global__ void scatter_kernel(const float* __restrict__ x, const int* __restrict__ dst,
                               float* __restrict__ xt) {
    int s = blockIdx.x;
    int d = dst[s];
    if (d < 0) return;
    int t = s >> 1;
    const float4* src = (const float4*)(x + (size_t)t*HDIM);
    float4* dp = (float4*)(xt + (size_t)d*HDIM);
    for (int i = threadIdx.x; i < HDIM/4; i += 256) dp[i] = src[i];
}

// ---------------- Final combine: out = h1 + sum_k p_k * fc2[dst_k] ----------------
__global__ void combine_kernel(const float* __restrict__ h1, const float* __restrict__ fc2,
                               const int* __restrict__ dst, const float* __restrict__ expp,
                               float* __restrict__ out) {
    int t = blockIdx.x;
    int d0 = dst[t*2], d1 = dst[t*2+1];
    float p0 = expp[t*2], p1 = expp[t*2+1];
    for (int i = threadIdx.x; i < HDIM; i += 256) {
        float v = h1[(size_t)t*HDIM + i];
        if (d0 >= 0) v += p0 * fc2[(size_t)d0*HDIM + i];
        if (d1 >= 0) v += p1 * fc2[(size_t)d1*HDIM + i];
        out[(size_t)t*HDIM + i] = v;
    }
}

extern "C" void kernel_launch(void* const* d_in, const int* in_sizes, int n_in,
                              void* d_out, int out_size, void* d_ws, size_t ws_size,
                              hipStream_t stream) {
    const float* hidden = (const float*)d_in[0];
    const float* ln1w   = (const float*)d_in[1];
    const float* ln1b   = (const float*)d_in[2];
    const float* ln2w   = (const float*)d_in[3];
    const float* ln2b   = (const float*)d_in[4];
    const float* qkvW   = (const float*)d_in[5];
    const float* projW  = (const float*)d_in[6];
    const float* routW  = (const float*)d_in[7];
    const float* w1     = (const float*)d_in[8];
    const float* w2     = (const float*)d_in[9];
    float* out = (float*)d_out;

    float* ws = (float*)d_ws;
    size_t off = 0;
    float* ln1 = ws + off; off += (size_t)S_LEN * HDIM;          // 2M
    float* qkv = ws + off; off += (size_t)S_LEN * QKV_O;         // 3M
    float* ao  = ws + off; off += (size_t)S_LEN * HDIM;          // 2M
    float* h1  = ws + off; off += (size_t)S_LEN * HDIM;          // 2M
    float* x2  = ln1;                                            // reuse (ln1 dead after qkv)
    float* xt  = ws + off; off += (size_t)TCAP * HDIM;           // 5.24M
    float* fc1 = ws + off; off += (size_t)TCAP * FDIM;           // 10.5M
    float* fc2 = ws + off; off += (size_t)TCAP * HDIM;           // 5.24M
    int*   expi = (int*)(ws + off); off += S_LEN * TOPK;
    int*   dst  = (int*)(ws + off); off += S_LEN * TOPK;
    float* expp = ws + off; off += S_LEN * TOPK;

    // 1. LN1
    ln_kernel<<<S_LEN, 256, 0, stream>>>(hidden, ln1w, ln1b, ln1);
    // 2. QKV = ln1 @ qkvW^T   [2048,1536]
    gemm_kernel<true,0><<<dim3(QKV_O/64, S_LEN/64, 1), 256, 0, stream>>>(
        ln1, qkvW, nullptr, qkv, S_LEN, QKV_O, HDIM, 0, 0, 0);
    // 3. Attention
    attn_kernel<<<dim3(S_LEN, NHEAD), 256, 0, stream>>>(qkv, ao);
    // 4. h1 = hidden + ao @ projW^T
    gemm_kernel<true,1><<<dim3(HDIM/64, S_LEN/64, 1), 256, 0, stream>>>(
        ao, projW, hidden, h1, S_LEN, HDIM, HDIM, 0, 0, 0);
    // 5. LN2
    ln_kernel<<<S_LEN, 256, 0, stream>>>(h1, ln2w, ln2b, x2);
    // 6. Router
    router_kernel<<<S_LEN, 256, 0, stream>>>(x2, routW, expi, expp);
    // 7. slot positions
    dst_kernel<<<(S_LEN*TOPK + 255)/256, 256, 0, stream>>>(expi, dst);
    // 8. zero + scatter
    hipMemsetAsync(xt, 0, (size_t)TCAP * HDIM * sizeof(float), stream);
    scatter_kernel<<<S_LEN*TOPK, 256, 0, stream>>>(x2, dst, xt);
    // 9. FC1 = gelu(xt @ w1[e])  per expert: [640,1024]x[1024,2048]
    gemm_kernel<false,2><<<dim3(FDIM/64, CAP/64, NEXP), 256, 0, stream>>>(
        xt, w1, nullptr, fc1, CAP, FDIM, HDIM,
        (long)CAP*HDIM, (long)HDIM*FDIM, (long)CAP*FDIM);
    // 10. FC2 = fc1 @ w2[e]  [640,2048]x[2048,1024]
    gemm_kernel<false,0><<<dim3(HDIM/64, CAP/64, NEXP), 256, 0, stream>>>(
        fc1, w2, nullptr, fc2, CAP, HDIM, FDIM,
        (long)CAP*FDIM, (long)FDIM*HDIM, (long)CAP*HDIM);
    // 11. combine
    combine_kernel<<<S_LEN, 256, 0, stream>>>(h1, fc2, dst, expp, out);
}

// Round 2
// 1038.070 us; speedup vs baseline: 2.2598x; 2.2598x over previous
//
#include <hip/hip_runtime.h>
#include <hip/hip_bf16.h>

#define S_LEN 2048
#define HDIM  1024
#define NHEAD 16
#define NKVH  4
#define HEADD 64
#define QKV_O 1536   // NKV*(q_per_kv+2)*HD = 4*6*64
#define NEXP  8
#define TOPK  2
#define CAP   640    // ceil(2048*2/8*1.25)
#define TCAP  (NEXP*CAP)
#define FDIM  2048
#define LOG2E 1.44269504088896f

typedef __bf16 bf16x8 __attribute__((ext_vector_type(8)));
typedef float  f32x4  __attribute__((ext_vector_type(4)));

// ---------------- LayerNorm ----------------
__global__ void ln_kernel(const float* __restrict__ in, const float* __restrict__ w,
                          const float* __restrict__ b, float* __restrict__ out) {
    int row = blockIdx.x;
    const float* x = in + (size_t)row * HDIM;
    float* o = out + (size_t)row * HDIM;
    __shared__ float red[256];
    int tid = threadIdx.x;
    float s = 0.f;
    for (int i = tid; i < HDIM; i += 256) s += x[i];
    red[tid] = s; __syncthreads();
    for (int st = 128; st > 0; st >>= 1) { if (tid < st) red[tid] += red[tid+st]; __syncthreads(); }
    float mu = red[0] / HDIM; __syncthreads();
    float v = 0.f;
    for (int i = tid; i < HDIM; i += 256) { float d = x[i]-mu; v += d*d; }
    red[tid] = v; __syncthreads();
    for (int st = 128; st > 0; st >>= 1) { if (tid < st) red[tid] += red[tid+st]; __syncthreads(); }
    float rstd = rsqrtf(red[0]/HDIM + 1e-5f);
    for (int i = tid; i < HDIM; i += 256) o[i] = (x[i]-mu)*rstd*w[i] + b[i];
}

// ---------------- GEMM: C[M,N] = A[M,K] * (BT ? W[N,K]^T : W[K,N]) ----------------
template<bool BT, int EPI>
__global__ __launch_bounds__(256)
void gemm_kernel(const float* __restrict__ A, const float* __restrict__ W,
                 const float* __restrict__ R, float* __restrict__ C,
                 int M, int N, int Kd,
                 long strideA, long strideW, long strideC) {
    __shared__ float As[16][68];
    __shared__ float Bs[16][68];
    int e = blockIdx.z;
    A += (size_t)e * strideA;
    W += (size_t)e * strideW;
    C += (size_t)e * strideC;
    int m0 = blockIdx.y * 64, n0 = blockIdx.x * 64;
    int tid = threadIdx.x;
    int tx = tid & 15, ty = tid >> 4;
    float c[4][4] = {};
    for (int k0 = 0; k0 < Kd; k0 += 16) {
        {
            int idx = tid * 4;
            int m = idx >> 4, kk = idx & 15;
            float4 a = *(const float4*)(A + (size_t)(m0+m)*Kd + k0 + kk);
            As[kk+0][m] = a.x; As[kk+1][m] = a.y; As[kk+2][m] = a.z; As[kk+3][m] = a.w;
        }
        if (BT) {
            int idx = tid * 4;
            int n = idx >> 4, kk = idx & 15;
            float4 b = *(const float4*)(W + (size_t)(n0+n)*Kd + k0 + kk);
            Bs[kk+0][n] = b.x; Bs[kk+1][n] = b.y; Bs[kk+2][n] = b.z; Bs[kk+3][n] = b.w;
        } else {
            int idx = tid * 4;
            int kk = idx >> 6, n = idx & 63;
            float4 b = *(const float4*)(W + (size_t)(k0+kk)*N + n0 + n);
            Bs[kk][n+0] = b.x; Bs[kk][n+1] = b.y; Bs[kk][n+2] = b.z; Bs[kk][n+3] = b.w;
        }
        __syncthreads();
        #pragma unroll
        for (int kk = 0; kk < 16; ++kk) {
            float av[4], bv[4];
            #pragma unroll
            for (int i = 0; i < 4; ++i) av[i] = As[kk][ty*4+i];
            #pragma unroll
            for (int j = 0; j < 4; ++j) bv[j] = Bs[kk][tx*4+j];
            #pragma unroll
            for (int i = 0; i < 4; ++i)
                #pragma unroll
                for (int j = 0; j < 4; ++j)
                    c[i][j] += av[i] * bv[j];
        }
        __syncthreads();
    }
    #pragma unroll
    for (int i = 0; i < 4; ++i) {
        int m = m0 + ty*4 + i;
        #pragma unroll
        for (int j = 0; j < 4; ++j) {
            int n = n0 + tx*4 + j;
            float v = c[i][j];
            if (EPI == 1) v += R[(size_t)m*N + n];
            if (EPI == 2) {
                float t = 0.7978845608028654f * (v + 0.044715f * v*v*v);
                v = 0.5f * v * (1.f + tanhf(t));
            }
            C[(size_t)m*N + n] = v;
        }
    }
}

// ---------------- MFMA flash attention ----------------
// grid (S/64, NH), 256 threads. Wave w owns q rows [q0+16w, q0+16w+16).
// K staged [kv][d] bf16, V staged transposed [d][kv] bf16, both XOR-swizzled.
__global__ __launch_bounds__(256)
void attn_mfma_kernel(const float* __restrict__ qkv, float* __restrict__ ao) {
    int q0 = blockIdx.x * 64;
    int h  = blockIdx.y;
    int g = h >> 2, qi = h & 3;
    const int tid  = threadIdx.x;
    const int w    = tid >> 6;
    const int lane = tid & 63;
    const int lr   = lane & 15;   // col-ish index
    const int lg   = lane >> 4;   // group 0..3

    __shared__ __attribute__((aligned(16))) __bf16 Kls[64*64];   // [kv][d]  swz
    __shared__ __attribute__((aligned(16))) __bf16 Vls[64*64];   // [d][kv]  swz (V^T)
    __shared__ __attribute__((aligned(16))) __bf16 Pls[4][16*64];// per-wave [q][kv] swz

    // Q fragments: lane holds A[row=lr][k=lg*8+j+32*ks], row = local q
    int qrow = q0 + w*16 + lr;
    const float* qp = qkv + (size_t)qrow*QKV_O + g*384 + qi*64;
    bf16x8 qfrag[2];
    #pragma unroll
    for (int ks = 0; ks < 2; ++ks) {
        const float* p = qp + ks*32 + lg*8;
        float4 f0 = *(const float4*)(p);
        float4 f1 = *(const float4*)(p + 4);
        qfrag[ks][0] = (__bf16)(f0.x*0.125f); qfrag[ks][1] = (__bf16)(f0.y*0.125f);
        qfrag[ks][2] = (__bf16)(f0.z*0.125f); qfrag[ks][3] = (__bf16)(f0.w*0.125f);
        qfrag[ks][4] = (__bf16)(f1.x*0.125f); qfrag[ks][5] = (__bf16)(f1.y*0.125f);
        qfrag[ks][6] = (__bf16)(f1.z*0.125f); qfrag[ks][7] = (__bf16)(f1.w*0.125f);
    }

    f32x4 oacc[4] = {};             // [ct]: d = lr+16ct ; reg r: q row = 4*lg+r
    float mrow[4] = {-INFINITY,-INFINITY,-INFINITY,-INFINITY};
    float lrow[4] = {0.f,0.f,0.f,0.f};

    int ntiles = q0/64 + 1;
    for (int t = 0; t < ntiles; ++t) {
        int kv0 = t*64;
        __syncthreads();   // previous tile's LDS readers done
        // ---- stage K tile: thread: kv=tid>>2, d-chunk dq=tid&3 (16 d each)
        {
            int kv = tid >> 2, dq = tid & 3;
            const float* kp = qkv + (size_t)(kv0+kv)*QKV_O + g*384 + 256 + dq*16;
            __bf16 tmp[16];
            #pragma unroll
            for (int j2 = 0; j2 < 16; j2 += 4) {
                float4 f = *(const float4*)(kp + j2);
                tmp[j2]=(__bf16)f.x; tmp[j2+1]=(__bf16)f.y; tmp[j2+2]=(__bf16)f.z; tmp[j2+3]=(__bf16)f.w;
            }
            int base = kv*128 + dq*32;
            int swz  = (kv & 7) << 4;
            *(bf16x8*)((char*)Kls + ((base     ) ^ swz)) = *(bf16x8*)tmp;
            *(bf16x8*)((char*)Kls + ((base + 16) ^ swz)) = *(bf16x8*)(tmp+8);
        }
        // ---- stage V^T: thread: kv pair p2=tid&31 (rows 2p2,2p2+1), d-chunk dg=tid>>5 (8 d)
        {
            int p2 = tid & 31, dg = tid >> 5;
            const float* v0 = qkv + (size_t)(kv0+2*p2)*QKV_O + g*384 + 320 + dg*8;
            const float* v1 = v0 + QKV_O;
            float a0[8], a1[8];
            *(float4*)a0 = *(const float4*)v0; *(float4*)(a0+4) = *(const float4*)(v0+4);
            *(float4*)a1 = *(const float4*)v1; *(float4*)(a1+4) = *(const float4*)(v1+4);
            #pragma unroll
            for (int j2 = 0; j2 < 8; ++j2) {
                int d = dg*8 + j2;
                unsigned short u0 = __builtin_bit_cast(unsigned short, (__bf16)a0[j2]);
                unsigned short u1 = __builtin_bit_cast(unsigned short, (__bf16)a1[j2]);
                unsigned u = ((unsigned)u1 << 16) | u0;
                *(unsigned*)((char*)Vls + ((d*128 + p2*4) ^ ((d&7)<<4))) = u;
            }
        }
        __syncthreads();

        // ---- S = Q K^T : 4 kv col-tiles x 2 k-steps
        f32x4 sacc[4] = {};
        #pragma unroll
        for (int f = 0; f < 4; ++f) {
            int row = lr + 16*f;             // kv row in K tile
            int swz = (row & 7) << 4;
            #pragma unroll
            for (int ks = 0; ks < 2; ++ks) {
                bf16x8 kf = *(const bf16x8*)((const char*)Kls + ((row*128 + (lg*8+32*ks)*2) ^ swz));
                sacc[f] = __builtin_amdgcn_mfma_f32_16x16x32_bf16(qfrag[ks], kf, sacc[f], 0,0,0);
            }
        }
        // ---- causal mask on diagonal tile
        if (t == ntiles-1) {
            #pragma unroll
            for (int f = 0; f < 4; ++f)
                #pragma unroll
                for (int r = 0; r < 4; ++r)
                    if (lr + 16*f > 16*w + 4*lg + r) sacc[f][r] = -INFINITY;
        }
        // ---- online softmax (rows r: q = 4*lg+r; reduce over lr lanes)
        float tm[4];
        #pragma unroll
        for (int r = 0; r < 4; ++r)
            tm[r] = fmaxf(fmaxf(sacc[0][r], sacc[1][r]), fmaxf(sacc[2][r], sacc[3][r]));
        #pragma unroll
        for (int msk = 1; msk < 16; msk <<= 1)
            #pragma unroll
            for (int r = 0; r < 4; ++r) tm[r] = fmaxf(tm[r], __shfl_xor(tm[r], msk, 64));
        float corr[4];
        #pragma unroll
        for (int r = 0; r < 4; ++r) {
            float mn = fmaxf(mrow[r], tm[r]);
            corr[r] = exp2f((mrow[r]-mn)*LOG2E);
            mrow[r] = mn;
        }
        float tl[4] = {0.f,0.f,0.f,0.f};
        #pragma unroll
        for (int f = 0; f < 4; ++f)
            #pragma unroll
            for (int r = 0; r < 4; ++r) {
                float p = exp2f((sacc[f][r]-mrow[r])*LOG2E);
                sacc[f][r] = p; tl[r] += p;
            }
        #pragma unroll
        for (int msk = 1; msk < 16; msk <<= 1)
            #pragma unroll
            for (int r = 0; r < 4; ++r) tl[r] += __shfl_xor(tl[r], msk, 64);
        #pragma unroll
        for (int r = 0; r < 4; ++r) lrow[r] = lrow[r]*corr[r] + tl[r];
        #pragma unroll
        for (int ct = 0; ct < 4; ++ct)
            #pragma unroll
            for (int r = 0; r < 4; ++r) oacc[ct][r] *= corr[r];
        // ---- write P (bf16) to per-wave LDS in C-layout, re-read as A-frags
        #pragma unroll
        for (int f = 0; f < 4; ++f)
            #pragma unroll
            for (int r = 0; r < 4; ++r) {
                int row = 4*lg + r, col = lr + 16*f;
                *(__bf16*)((char*)&Pls[w][0] + ((row*128 + col*2) ^ ((row&7)<<4))) = (__bf16)sacc[f][r];
            }
        __syncthreads();
        // ---- O += P V : A=P[q][kv], B=V^T-read
        bf16x8 pa[2];
        #pragma unroll
        for (int ks = 0; ks < 2; ++ks)
            pa[ks] = *(const bf16x8*)((const char*)&Pls[w][0] + ((lr*128 + (lg*8+32*ks)*2) ^ ((lr&7)<<4)));
        #pragma unroll
        for (int ct = 0; ct < 4; ++ct) {
            int row = lr + 16*ct;            // d row in V^T tile
            int swz = (row & 7) << 4;
            #pragma unroll
            for (int ks = 0; ks < 2; ++ks) {
                bf16x8 vf = *(const bf16x8*)((const char*)Vls + ((row*128 + (lg*8+32*ks)*2) ^ swz));
                oacc[ct] = __builtin_amdgcn_mfma_f32_16x16x32_bf16(pa[ks], vf, oacc[ct], 0,0,0);
            }
        }
    }
    // ---- epilogue
    #pragma unroll
    for (int ct = 0; ct < 4; ++ct)
        #pragma unroll
        for (int r = 0; r < 4; ++r) {
            int q = q0 + 16*w + 4*lg + r;
            ao[(size_t)q*HDIM + h*64 + 16*ct + lr] = oacc[ct][r] / lrow[r];
        }
}

// ---------------- Router ----------------
__global__ __launch_bounds__(256)
void router_kernel(const float* __restrict__ x, const float* __restrict__ rw,
                   int* __restrict__ expi, float* __restrict__ expp) {
    int t = blockIdx.x, tid = threadIdx.x;
    __shared__ float red[256][8];
    float part[8] = {};
    const float* xr = x + (size_t)t*HDIM;
    for (int i = tid; i < HDIM; i += 256) {
        float xv = xr[i];
        const float* wp = rw + (size_t)i*NEXP;
        #pragma unroll
        for (int e2 = 0; e2 < 8; ++e2) part[e2] += xv * wp[e2];
    }
    #pragma unroll
    for (int e2 = 0; e2 < 8; ++e2) red[tid][e2] = part[e2];
    __syncthreads();
    for (int st = 128; st > 0; st >>= 1) {
        if (tid < st)
            #pragma unroll
            for (int e2 = 0; e2 < 8; ++e2) red[tid][e2] += red[tid+st][e2];
        __syncthreads();
    }
    if (tid == 0) {
        float lg[8];
        #pragma unroll
        for (int e2 = 0; e2 < 8; ++e2) lg[e2] = red[0][e2];
        int i0 = 0;
        for (int e2 = 1; e2 < 8; ++e2) if (lg[e2] > lg[i0]) i0 = e2;
        int i1 = -1;
        for (int e2 = 0; e2 < 8; ++e2) { if (e2 == i0) continue; if (i1 < 0 || lg[e2] > lg[i1]) i1 = e2; }
        float p1 = __expf(lg[i1] - lg[i0]);
        float inv = 1.f / (1.f + p1);
        expi[t*2]   = i0; expi[t*2+1] = i1;
        expp[t*2]   = inv; expp[t*2+1] = p1 * inv;
    }
}

// ---------------- Slot -> destination ----------------
__global__ void dst_kernel(const int* __restrict__ expi, int* __restrict__ dst) {
    int s = blockIdx.x * blockDim.x + threadIdx.x;
    if (s >= S_LEN * TOPK) return;
    int e = expi[s];
    int within = 0;
    for (int i = 0; i < s; ++i) within += (expi[i] == e);
    dst[s] = (within < CAP) ? (e * CAP + within) : -1;
}

// ---------------- Scatter ----------------
__global__ void scatter_kernel(const float* __restrict__ x, const int* __restrict__ dst,
                               float* __restrict__ xt) {
    int s = blockIdx.x;
    int d = dst[s];
    if (d < 0) return;
    int t = s >> 1;
    const float4* src = (const float4*)(x + (size_t)t*HDIM);
    float4* dp = (float4*)(xt + (size_t)d*HDIM);
    for (int i = threadIdx.x; i < HDIM/4; i += 256) dp[i] = src[i];
}

// ---------------- Combine ----------------
__global__ void combine_kernel(const float* __restrict__ h1, const float* __restrict__ fc2,
                               const int* __restrict__ dst, const float* __restrict__ expp,
                               float* __restrict__ out) {
    int t = blockIdx.x;
    int d0 = dst[t*2], d1 = dst[t*2+1];
    float p0 = expp[t*2], p1 = expp[t*2+1];
    for (int i = threadIdx.x; i < HDIM; i += 256) {
        float v = h1[(size_t)t*HDIM + i];
        if (d0 >= 0) v += p0 * fc2[(size_t)d0*HDIM + i];
        if (d1 >= 0) v += p1 * fc2[(size_t)d1*HDIM + i];
        out[(size_t)t*HDIM + i] = v;
    }
}

extern "C" void kernel_launch(void* const* d_in, const int* in_sizes, int n_in,
                              void* d_out, int out_size, void* d_ws, size_t ws_size,
                              hipStream_t stream) {
    const float* hidden = (const float*)d_in[0];
    const float* ln1w   = (const float*)d_in[1];
    const float* ln1b   = (const float*)d_in[2];
    const float* ln2w   = (const float*)d_in[3];
    const float* ln2b   = (const float*)d_in[4];
    const float* qkvW   = (const float*)d_in[5];
    const float* projW  = (const float*)d_in[6];
    const float* routW  = (const float*)d_in[7];
    const float* w1     = (const float*)d_in[8];
    const float* w2     = (const float*)d_in[9];
    float* out = (float*)d_out;

    float* ws = (float*)d_ws;
    size_t off = 0;
    float* ln1 = ws + off; off += (size_t)S_LEN * HDIM;
    float* qkv = ws + off; off += (size_t)S_LEN * QKV_O;
    float* ao  = ws + off; off += (size_t)S_LEN * HDIM;
    float* h1  = ws + off; off += (size_t)S_LEN * HDIM;
    float* x2  = ln1;
    float* xt  = ws + off; off += (size_t)TCAP * HDIM;
    float* fc1 = ws + off; off += (size_t)TCAP * FDIM;
    float* fc2 = ws + off; off += (size_t)TCAP * HDIM;
    int*   expi = (int*)(ws + off); off += S_LEN * TOPK;
    int*   dst  = (int*)(ws + off); off += S_LEN * TOPK;
    float* expp = ws + off; off += S_LEN * TOPK;

    ln_kernel<<<S_LEN, 256, 0, stream>>>(hidden, ln1w, ln1b, ln1);
    gemm_kernel<true,0><<<dim3(QKV_O/64, S_LEN/64, 1), 256, 0, stream>>>(
        ln1, qkvW, nullptr, qkv, S_LEN, QKV_O, HDIM, 0, 0, 0);
    attn_mfma_kernel<<<dim3(S_LEN/64, NHEAD), 256, 0, stream>>>(qkv, ao);
    gemm_kernel<true,1><<<dim3(HDIM/64, S_LEN/64, 1), 256, 0, stream>>>(
        ao, projW, hidden, h1, S_LEN, HDIM, HDIM, 0, 0, 0);
    ln_kernel<<<S_LEN, 256, 0, stream>>>(h1, ln2w, ln2b, x2);
    router_kernel<<<S_LEN, 256, 0, stream>>>(x2, routW, expi, expp);
    dst_kernel<<<(S_LEN*TOPK + 255)/256, 256, 0, stream>>>(expi, dst);
    hipMemsetAsync(xt, 0, (size_t)TCAP * HDIM * sizeof(float), stream);
    scatter_kernel<<<S_LEN*TOPK, 256, 0, stream>>>(x2, dst, xt);
    gemm_kernel<false,2><<<dim3(FDIM/64, CAP/64, NEXP), 256, 0, stream>>>(
        xt, w1, nullptr, fc1, CAP, FDIM, HDIM,
        (long)CAP*HDIM, (long)HDIM*FDIM, (long)CAP*FDIM);
    gemm_kernel<false,0><<<dim3(HDIM/64, CAP/64, NEXP), 256, 0, stream>>>(
        fc1, w2, nullptr, fc2, CAP, HDIM, FDIM,
        (long)CAP*FDIM, (long)FDIM*HDIM, (long)CAP*HDIM);
    combine_kernel<<<S_LEN, 256, 0, stream>>>(h1, fc2, dst, expp, out);
}

// Round 3
// 465.101 us; speedup vs baseline: 5.0437x; 2.2319x over previous
//
#include <hip/hip_runtime.h>
#include <hip/hip_bf16.h>
#include <stdint.h>

#define S_LEN 2048
#define HDIM  1024
#define NHEAD 16
#define NKVH  4
#define HEADD 64
#define QKV_O 1536   // NKV*(q_per_kv+2)*HD = 4*6*64
#define NEXP  8
#define TOPK  2
#define CAP   640    // ceil(2048*2/8*1.25)
#define TCAP  (NEXP*CAP)
#define FDIM  2048
#define LOG2E 1.44269504088896f

typedef __bf16 bf16x8 __attribute__((ext_vector_type(8)));
typedef float  f32x4  __attribute__((ext_vector_type(4)));
typedef unsigned int u32;
typedef u32 u32x4 __attribute__((ext_vector_type(4)));
typedef unsigned short u16;
typedef u16 u16x8 __attribute__((ext_vector_type(8)));

// ---------------- LayerNorm (templated output dtype) ----------------
template<bool BF>
__global__ void ln_kernel(const float* __restrict__ in, const float* __restrict__ w,
                          const float* __restrict__ b, void* __restrict__ outv) {
    int row = blockIdx.x;
    const float* x = in + (size_t)row * HDIM;
    __shared__ float red[256];
    int tid = threadIdx.x;
    float s = 0.f;
    for (int i = tid; i < HDIM; i += 256) s += x[i];
    red[tid] = s; __syncthreads();
    for (int st = 128; st > 0; st >>= 1) { if (tid < st) red[tid] += red[tid+st]; __syncthreads(); }
    float mu = red[0] / HDIM; __syncthreads();
    float v = 0.f;
    for (int i = tid; i < HDIM; i += 256) { float d = x[i]-mu; v += d*d; }
    red[tid] = v; __syncthreads();
    for (int st = 128; st > 0; st >>= 1) { if (tid < st) red[tid] += red[tid+st]; __syncthreads(); }
    float rstd = rsqrtf(red[0]/HDIM + 1e-5f);
    for (int i = tid; i < HDIM; i += 256) {
        float o = (x[i]-mu)*rstd*w[i] + b[i];
        if (BF) ((__bf16*)outv)[(size_t)row*HDIM + i] = (__bf16)o;
        else    ((float*)outv)[(size_t)row*HDIM + i] = o;
    }
}

// ---------------- f32 -> bf16 convert (n8 = count/8) ----------------
__global__ void conv_bf16_kernel(const float* __restrict__ src, __bf16* __restrict__ dst, int n8) {
    int i = blockIdx.x*256 + threadIdx.x;
    if (i >= n8) return;
    const float4* s = (const float4*)src + (size_t)i*2;
    float4 a = s[0], b = s[1];
    __bf16 tmp[8] = {(__bf16)a.x,(__bf16)a.y,(__bf16)a.z,(__bf16)a.w,
                     (__bf16)b.x,(__bf16)b.y,(__bf16)b.z,(__bf16)b.w};
    *(u32x4*)(dst + (size_t)i*8) = *(u32x4*)tmp;
}

// ---------------- transpose + convert: dst[e][n][k] = (bf16) src[e][k][n] ----------------
__global__ __launch_bounds__(256)
void transp_conv_kernel(const float* __restrict__ src, __bf16* __restrict__ dst, int K, int N) {
    __shared__ float t[32][33];
    int e = blockIdx.z;
    src += (size_t)e * K * N;
    dst += (size_t)e * K * N;
    int n0 = blockIdx.x*32, k0 = blockIdx.y*32;
    int tx = threadIdx.x & 31, ty = threadIdx.x >> 5;
    #pragma unroll
    for (int i = 0; i < 32; i += 8)
        t[ty+i][tx] = src[(size_t)(k0+ty+i)*N + n0 + tx];
    __syncthreads();
    #pragma unroll
    for (int i = 0; i < 32; i += 8)
        dst[(size_t)(n0+ty+i)*K + k0 + tx] = (__bf16)t[tx][ty+i];
}

// ---------------- bf16 MFMA GEMM: C[M,N] = A[M,K] * Bt[N,K]^T ----------------
// 128x128 tile, BK=64, 4 waves (2x2 of 64x64), 16x16x32 MFMA.
// EPI: 0=f32 out, 1=f32 out + residual R, 2=gelu->bf16 out, 3=bf16 out
template<int EPI>
__global__ __launch_bounds__(256)
void gemm_bf16_kernel(const __bf16* __restrict__ A, const __bf16* __restrict__ Bt,
                      const float* __restrict__ R, void* __restrict__ Cout,
                      int N, int K, long sA, long sB, long sC) {
    __shared__ __bf16 As[128*64];   // [row][k], 16B-granule XOR swizzle
    __shared__ __bf16 Bs[128*64];
    const int e = blockIdx.z;
    A  += (size_t)e * sA;
    Bt += (size_t)e * sB;
    const int m0 = blockIdx.y*128, n0 = blockIdx.x*128;
    const int tid = threadIdx.x;
    const int lane = tid & 63, w = tid >> 6;
    const int lr = lane & 15, lg = lane >> 4;
    const int wr = w >> 1, wc = w & 1;
    const int srow = tid >> 3, sc = tid & 7;     // staging: rows srow+{0,32,64,96}, 16B granule sc
    f32x4 acc[4][4] = {};
    for (int k0 = 0; k0 < K; k0 += 64) {
        __syncthreads();
        #pragma unroll
        for (int i = 0; i < 4; ++i) {
            int row = srow + i*32;
            int lof = (row*128 + sc*16) ^ ((row&7)<<4);
            u32x4 va = *(const u32x4*)(A  + (size_t)(m0+row)*K + k0 + sc*8);
            *(u32x4*)((char*)As + lof) = va;
            u32x4 vb = *(const u32x4*)(Bt + (size_t)(n0+row)*K + k0 + sc*8);
            *(u32x4*)((char*)Bs + lof) = vb;
        }
        __syncthreads();
        #pragma unroll
        for (int ks = 0; ks < 2; ++ks) {
            bf16x8 af[4], bfr[4];
            #pragma unroll
            for (int mi = 0; mi < 4; ++mi) {
                int row = wr*64 + mi*16 + lr;
                af[mi] = *(const bf16x8*)((const char*)As + ((row*128 + (lg+4*ks)*16) ^ ((row&7)<<4)));
            }
            #pragma unroll
            for (int ni = 0; ni < 4; ++ni) {
                int row = wc*64 + ni*16 + lr;
                bfr[ni] = *(const bf16x8*)((const char*)Bs + ((row*128 + (lg+4*ks)*16) ^ ((row&7)<<4)));
            }
            #pragma unroll
            for (int mi = 0; mi < 4; ++mi)
                #pragma unroll
                for (int ni = 0; ni < 4; ++ni)
                    acc[mi][ni] = __builtin_amdgcn_mfma_f32_16x16x32_bf16(af[mi], bfr[ni], acc[mi][ni], 0,0,0);
        }
    }
    #pragma unroll
    for (int mi = 0; mi < 4; ++mi) {
        #pragma unroll
        for (int ni = 0; ni < 4; ++ni) {
            #pragma unroll
            for (int r = 0; r < 4; ++r) {
                int row = m0 + wr*64 + mi*16 + lg*4 + r;
                int col = n0 + wc*64 + ni*16 + lr;
                float v = acc[mi][ni][r];
                if (EPI == 1) v += R[(size_t)row*N + col];
                if (EPI == 2) {
                    float t = 0.7978845608028654f * (v + 0.044715f*v*v*v);
                    v = 0.5f * v * (1.f + tanhf(t));
                }
                if (EPI == 2 || EPI == 3)
                    ((__bf16*)Cout)[(size_t)e*sC + (size_t)row*N + col] = (__bf16)v;
                else
                    ((float*)Cout)[(size_t)e*sC + (size_t)row*N + col] = v;
            }
        }
    }
}

// ---------------- MFMA flash attention (bf16 qkv in, bf16 ao out) ----------------
__global__ __launch_bounds__(256)
void attn_mfma_kernel(const __bf16* __restrict__ qkv, __bf16* __restrict__ ao) {
    int q0 = blockIdx.x * 64;
    int h  = blockIdx.y;
    int hg = h >> 2, qi = h & 3;
    const int tid  = threadIdx.x;
    const int w    = tid >> 6;
    const int lane = tid & 63;
    const int lr   = lane & 15;
    const int lg   = lane >> 4;

    __shared__ __attribute__((aligned(16))) __bf16 Kls[64*64];   // [kv][d]  swz
    __shared__ __attribute__((aligned(16))) __bf16 Vls[64*64];   // [d][kv]  swz (V^T)
    __shared__ __attribute__((aligned(16))) __bf16 Pls[4][16*64];

    int qrow = q0 + w*16 + lr;
    const __bf16* qp = qkv + (size_t)qrow*QKV_O + hg*384 + qi*64;
    bf16x8 qfrag[2];
    #pragma unroll
    for (int ks = 0; ks < 2; ++ks) {
        bf16x8 qr = *(const bf16x8*)(qp + ks*32 + lg*8);
        #pragma unroll
        for (int j = 0; j < 8; ++j) qfrag[ks][j] = (__bf16)((float)qr[j] * 0.125f);
    }

    f32x4 oacc[4] = {};
    float mrow[4] = {-INFINITY,-INFINITY,-INFINITY,-INFINITY};
    float lrow[4] = {0.f,0.f,0.f,0.f};

    int ntiles = q0/64 + 1;
    for (int t = 0; t < ntiles; ++t) {
        int kv0 = t*64;
        __syncthreads();
        // ---- stage K: granules g = tid, tid+256 : row=g>>3, c=g&7
        #pragma unroll
        for (int i = 0; i < 2; ++i) {
            int g2 = tid + i*256;
            int row = g2 >> 3, c = g2 & 7;
            u32x4 v = *(const u32x4*)(qkv + (size_t)(kv0+row)*QKV_O + hg*384 + 256 + c*8);
            *(u32x4*)((char*)Kls + ((row*128 + c*16) ^ ((row&7)<<4))) = v;
        }
        // ---- stage V^T: kv pair p2, 8 d's
        {
            int p2 = tid & 31, dg = tid >> 5;
            const __bf16* v0p = qkv + (size_t)(kv0+2*p2)*QKV_O + hg*384 + 320 + dg*8;
            u16x8 a0 = *(const u16x8*)v0p;
            u16x8 a1 = *(const u16x8*)(v0p + QKV_O);
            #pragma unroll
            for (int j2 = 0; j2 < 8; ++j2) {
                int d = dg*8 + j2;
                u32 u = ((u32)a1[j2] << 16) | a0[j2];
                *(u32*)((char*)Vls + ((d*128 + p2*4) ^ ((d&7)<<4))) = u;
            }
        }
        __syncthreads();

        // ---- S = Q K^T
        f32x4 sacc[4] = {};
        #pragma unroll
        for (int f = 0; f < 4; ++f) {
            int row = lr + 16*f;
            int swz = (row & 7) << 4;
            #pragma unroll
            for (int ks = 0; ks < 2; ++ks) {
                bf16x8 kf = *(const bf16x8*)((const char*)Kls + ((row*128 + (lg*8+32*ks)*2) ^ swz));
                sacc[f] = __builtin_amdgcn_mfma_f32_16x16x32_bf16(qfrag[ks], kf, sacc[f], 0,0,0);
            }
        }
        if (t == ntiles-1) {
            #pragma unroll
            for (int f = 0; f < 4; ++f)
                #pragma unroll
                for (int r = 0; r < 4; ++r)
                    if (lr + 16*f > 16*w + 4*lg + r) sacc[f][r] = -INFINITY;
        }
        float tm[4];
        #pragma unroll
        for (int r = 0; r < 4; ++r)
            tm[r] = fmaxf(fmaxf(sacc[0][r], sacc[1][r]), fmaxf(sacc[2][r], sacc[3][r]));
        #pragma unroll
        for (int msk = 1; msk < 16; msk <<= 1)
            #pragma unroll
            for (int r = 0; r < 4; ++r) tm[r] = fmaxf(tm[r], __shfl_xor(tm[r], msk, 64));
        float corr[4];
        #pragma unroll
        for (int r = 0; r < 4; ++r) {
            float mn = fmaxf(mrow[r], tm[r]);
            corr[r] = exp2f((mrow[r]-mn)*LOG2E);
            mrow[r] = mn;
        }
        float tl[4] = {0.f,0.f,0.f,0.f};
        #pragma unroll
        for (int f = 0; f < 4; ++f)
            #pragma unroll
            for (int r = 0; r < 4; ++r) {
                float p = exp2f((sacc[f][r]-mrow[r])*LOG2E);
                sacc[f][r] = p; tl[r] += p;
            }
        #pragma unroll
        for (int msk = 1; msk < 16; msk <<= 1)
            #pragma unroll
            for (int r = 0; r < 4; ++r) tl[r] += __shfl_xor(tl[r], msk, 64);
        #pragma unroll
        for (int r = 0; r < 4; ++r) lrow[r] = lrow[r]*corr[r] + tl[r];
        #pragma unroll
        for (int ct = 0; ct < 4; ++ct)
            #pragma unroll
            for (int r = 0; r < 4; ++r) oacc[ct][r] *= corr[r];
        #pragma unroll
        for (int f = 0; f < 4; ++f)
            #pragma unroll
            for (int r = 0; r < 4; ++r) {
                int row = 4*lg + r, col = lr + 16*f;
                *(__bf16*)((char*)&Pls[w][0] + ((row*128 + col*2) ^ ((row&7)<<4))) = (__bf16)sacc[f][r];
            }
        __syncthreads();
        bf16x8 pa[2];
        #pragma unroll
        for (int ks = 0; ks < 2; ++ks)
            pa[ks] = *(const bf16x8*)((const char*)&Pls[w][0] + ((lr*128 + (lg*8+32*ks)*2) ^ ((lr&7)<<4)));
        #pragma unroll
        for (int ct = 0; ct < 4; ++ct) {
            int row = lr + 16*ct;
            int swz = (row & 7) << 4;
            #pragma unroll
            for (int ks = 0; ks < 2; ++ks) {
                bf16x8 vf = *(const bf16x8*)((const char*)Vls + ((row*128 + (lg*8+32*ks)*2) ^ swz));
                oacc[ct] = __builtin_amdgcn_mfma_f32_16x16x32_bf16(pa[ks], vf, oacc[ct], 0,0,0);
            }
        }
    }
    #pragma unroll
    for (int ct = 0; ct < 4; ++ct)
        #pragma unroll
        for (int r = 0; r < 4; ++r) {
            int q = q0 + 16*w + 4*lg + r;
            ao[(size_t)q*HDIM + h*64 + 16*ct + lr] = (__bf16)(oacc[ct][r] / lrow[r]);
        }
}

// ---------------- Router (f32 exact — expert decisions must match reference) ----------------
__global__ __launch_bounds__(256)
void router_kernel(const float* __restrict__ x, const float* __restrict__ rw,
                   int* __restrict__ expi, float* __restrict__ expp) {
    int t = blockIdx.x, tid = threadIdx.x;
    __shared__ float red[256][8];
    float part[8] = {};
    const float* xr = x + (size_t)t*HDIM;
    for (int i = tid; i < HDIM; i += 256) {
        float xv = xr[i];
        const float* wp = rw + (size_t)i*NEXP;
        #pragma unroll
        for (int e2 = 0; e2 < 8; ++e2) part[e2] += xv * wp[e2];
    }
    #pragma unroll
    for (int e2 = 0; e2 < 8; ++e2) red[tid][e2] = part[e2];
    __syncthreads();
    for (int st = 128; st > 0; st >>= 1) {
        if (tid < st)
            #pragma unroll
            for (int e2 = 0; e2 < 8; ++e2) red[tid][e2] += red[tid+st][e2];
        __syncthreads();
    }
    if (tid == 0) {
        float lg[8];
        #pragma unroll
        for (int e2 = 0; e2 < 8; ++e2) lg[e2] = red[0][e2];
        int i0 = 0;
        for (int e2 = 1; e2 < 8; ++e2) if (lg[e2] > lg[i0]) i0 = e2;
        int i1 = -1;
        for (int e2 = 0; e2 < 8; ++e2) { if (e2 == i0) continue; if (i1 < 0 || lg[e2] > lg[i1]) i1 = e2; }
        float p1 = __expf(lg[i1] - lg[i0]);
        float inv = 1.f / (1.f + p1);
        expi[t*2]   = i0; expi[t*2+1] = i1;
        expp[t*2]   = inv; expp[t*2+1] = p1 * inv;
    }
}

// ---------------- Slot -> destination ----------------
__global__ void dst_kernel(const int* __restrict__ expi, int* __restrict__ dst) {
    int s = blockIdx.x * blockDim.x + threadIdx.x;
    if (s >= S_LEN * TOPK) return;
    int e = expi[s];
    int within = 0;
    for (int i = 0; i < s; ++i) within += (expi[i] == e);
    dst[s] = (within < CAP) ? (e * CAP + within) : -1;
}

// ---------------- Scatter (f32 x -> bf16 xt) ----------------
__global__ void scatter_kernel(const float* __restrict__ x, const int* __restrict__ dst,
                               __bf16* __restrict__ xt) {
    int s = blockIdx.x;
    int d = dst[s];
    if (d < 0) return;
    int t = s >> 1;
    int i = threadIdx.x;   // 256 threads x 4 elems = 1024
    float4 f = ((const float4*)(x + (size_t)t*HDIM))[i];
    __bf16* dp = xt + (size_t)d*HDIM + i*4;
    dp[0]=(__bf16)f.x; dp[1]=(__bf16)f.y; dp[2]=(__bf16)f.z; dp[3]=(__bf16)f.w;
}

// ---------------- Combine ----------------
__global__ void combine_kernel(const float* __restrict__ h1, const float* __restrict__ fc2,
                               const int* __restrict__ dst, const float* __restrict__ expp,
                               float* __restrict__ out) {
    int t = blockIdx.x;
    int d0 = dst[t*2], d1 = dst[t*2+1];
    float p0 = expp[t*2], p1 = expp[t*2+1];
    for (int i = threadIdx.x; i < HDIM; i += 256) {
        float v = h1[(size_t)t*HDIM + i];
        if (d0 >= 0) v += p0 * fc2[(size_t)d0*HDIM + i];
        if (d1 >= 0) v += p1 * fc2[(size_t)d1*HDIM + i];
        out[(size_t)t*HDIM + i] = v;
    }
}

extern "C" void kernel_launch(void* const* d_in, const int* in_sizes, int n_in,
                              void* d_out, int out_size, void* d_ws, size_t ws_size,
                              hipStream_t stream) {
    const float* hidden = (const float*)d_in[0];
    const float* ln1w   = (const float*)d_in[1];
    const float* ln1b_  = (const float*)d_in[2];
    const float* ln2w   = (const float*)d_in[3];
    const float* ln2b_  = (const float*)d_in[4];
    const float* qkvW   = (const float*)d_in[5];
    const float* projW  = (const float*)d_in[6];
    const float* routW  = (const float*)d_in[7];
    const float* w1     = (const float*)d_in[8];
    const float* w2     = (const float*)d_in[9];
    float* out = (float*)d_out;

    char* base = (char*)d_ws;
    // ---- ArenaA (67MB): w1t/w2t late; phase-1 bf16 buffers alias w1t's span (dead before transpose)
    __bf16* w1t    = (__bf16*)(base);                 // 33,554,432 B  [E][FDIM][HDIM]
    __bf16* w2t    = (__bf16*)(base + 33554432);      // 33,554,432 B  [E][HDIM][FDIM]
    __bf16* ln1b   = (__bf16*)(base + 0);             // 4 MB
    __bf16* qkvWb  = (__bf16*)(base + 4194304);       // 3 MB
    __bf16* qkvb   = (__bf16*)(base + 7340032);       // 6 MB
    __bf16* aob    = (__bf16*)(base + 13631488);      // 4 MB
    __bf16* projWb = (__bf16*)(base + 17825792);      // 2 MB
    // ---- ArenaB
    char* B0 = base + 67108864;
    float*  h1   = (float*)(B0);                      // 8 MB
    __bf16* xtb  = (__bf16*)(B0 + 8388608);           // 10.5 MB
    __bf16* fc1b = (__bf16*)(B0 + 18874368);          // 21 MB
    float*  fc2  = (float*)(B0 + 39845888);           // 21 MB
    float*  x2   = fc2;                               // alias: x2 dead before fc2 written
    int*    expi = (int*)(B0 + 60817408);
    int*    dsts = (int*)(B0 + 60833792);
    float*  expp = (float*)(B0 + 60850176);

    // 1. LN1 -> bf16
    ln_kernel<true><<<S_LEN, 256, 0, stream>>>(hidden, ln1w, ln1b_, ln1b);
    // 2. convert qkvW
    conv_bf16_kernel<<<(QKV_O*HDIM/8 + 255)/256, 256, 0, stream>>>(qkvW, qkvWb, QKV_O*HDIM/8);
    // 3. QKV (bf16 out)
    gemm_bf16_kernel<3><<<dim3(QKV_O/128, S_LEN/128, 1), 256, 0, stream>>>(
        ln1b, qkvWb, nullptr, qkvb, QKV_O, HDIM, 0, 0, 0);
    // 4. attention
    attn_mfma_kernel<<<dim3(S_LEN/64, NHEAD), 256, 0, stream>>>(qkvb, aob);
    // 5. convert projW
    conv_bf16_kernel<<<(HDIM*HDIM/8 + 255)/256, 256, 0, stream>>>(projW, projWb, HDIM*HDIM/8);
    // 6. h1 = hidden + ao @ projW^T
    gemm_bf16_kernel<1><<<dim3(HDIM/128, S_LEN/128, 1), 256, 0, stream>>>(
        aob, projWb, hidden, h1, HDIM, HDIM, 0, 0, 0);
    // 7. LN2 -> f32
    ln_kernel<false><<<S_LEN, 256, 0, stream>>>(h1, ln2w, ln2b_, x2);
    // 8. router
    router_kernel<<<S_LEN, 256, 0, stream>>>(x2, routW, expi, expp);
    // 9. slots
    dst_kernel<<<(S_LEN*TOPK + 255)/256, 256, 0, stream>>>(expi, dsts);
    // 10. zero + scatter (bf16)
    hipMemsetAsync(xtb, 0, (size_t)TCAP * HDIM * sizeof(__bf16), stream);
    scatter_kernel<<<S_LEN*TOPK, 256, 0, stream>>>(x2, dsts, xtb);
    // 11. transpose-convert MoE weights (phase-1 aliases dead now)
    transp_conv_kernel<<<dim3(FDIM/32, HDIM/32, NEXP), 256, 0, stream>>>(w1, w1t, HDIM, FDIM);
    transp_conv_kernel<<<dim3(HDIM/32, FDIM/32, NEXP), 256, 0, stream>>>(w2, w2t, FDIM, HDIM);
    // 12. FC1 = gelu(xt @ w1) -> bf16
    gemm_bf16_kernel<2><<<dim3(FDIM/128, CAP/128, NEXP), 256, 0, stream>>>(
        xtb, w1t, nullptr, fc1b, FDIM, HDIM,
        (long)CAP*HDIM, (long)FDIM*HDIM, (long)CAP*FDIM);
    // 13. FC2 = fc1 @ w2 -> f32
    gemm_bf16_kernel<0><<<dim3(HDIM/128, CAP/128, NEXP), 256, 0, stream>>>(
        fc1b, w2t, nullptr, fc2, HDIM, FDIM,
        (long)CAP*FDIM, (long)FDIM*HDIM, (long)CAP*HDIM);
    // 14. combine
    combine_kernel<<<S_LEN, 256, 0, stream>>>(h1, fc2, dsts, expp, out);
}

// Round 4
// 312.483 us; speedup vs baseline: 7.5071x; 1.4884x over previous
//
#include <hip/hip_runtime.h>
#include <hip/hip_bf16.h>
#include <stdint.h>

#define S_LEN 2048
#define HDIM  1024
#define NHEAD 16
#define NKVH  4
#define HEADD 64
#define QKV_O 1536   // NKV*(q_per_kv+2)*HD = 4*6*64
#define NEXP  8
#define TOPK  2
#define CAP   640    // ceil(2048*2/8*1.25)
#define TCAP  (NEXP*CAP)
#define FDIM  2048
#define LOG2E 1.44269504088896f

typedef __bf16 bf16x8 __attribute__((ext_vector_type(8)));
typedef float  f32x4  __attribute__((ext_vector_type(4)));
typedef unsigned int u32;
typedef u32 u32x4 __attribute__((ext_vector_type(4)));
typedef unsigned short u16;
typedef u16 u16x8 __attribute__((ext_vector_type(8)));

// ---------------- LayerNorm (templated output dtype) ----------------
template<bool BF>
__global__ void ln_kernel(const float* __restrict__ in, const float* __restrict__ w,
                          const float* __restrict__ b, void* __restrict__ outv) {
    int row = blockIdx.x;
    const float* x = in + (size_t)row * HDIM;
    __shared__ float red[256];
    int tid = threadIdx.x;
    float s = 0.f;
    for (int i = tid; i < HDIM; i += 256) s += x[i];
    red[tid] = s; __syncthreads();
    for (int st = 128; st > 0; st >>= 1) { if (tid < st) red[tid] += red[tid+st]; __syncthreads(); }
    float mu = red[0] / HDIM; __syncthreads();
    float v = 0.f;
    for (int i = tid; i < HDIM; i += 256) { float d = x[i]-mu; v += d*d; }
    red[tid] = v; __syncthreads();
    for (int st = 128; st > 0; st >>= 1) { if (tid < st) red[tid] += red[tid+st]; __syncthreads(); }
    float rstd = rsqrtf(red[0]/HDIM + 1e-5f);
    for (int i = tid; i < HDIM; i += 256) {
        float o = (x[i]-mu)*rstd*w[i] + b[i];
        if (BF) ((__bf16*)outv)[(size_t)row*HDIM + i] = (__bf16)o;
        else    ((float*)outv)[(size_t)row*HDIM + i] = o;
    }
}

// ---------------- f32 -> bf16 convert (n8 = count/8) ----------------
__global__ void conv_bf16_kernel(const float* __restrict__ src, __bf16* __restrict__ dst, int n8) {
    int i = blockIdx.x*256 + threadIdx.x;
    if (i >= n8) return;
    const float4* s = (const float4*)src + (size_t)i*2;
    float4 a = s[0], b = s[1];
    __bf16 tmp[8] = {(__bf16)a.x,(__bf16)a.y,(__bf16)a.z,(__bf16)a.w,
                     (__bf16)b.x,(__bf16)b.y,(__bf16)b.z,(__bf16)b.w};
    *(u32x4*)(dst + (size_t)i*8) = *(u32x4*)tmp;
}

// ---------------- transpose + convert: dst[e][n][k] = (bf16) src[e][k][n] ----------------
__global__ __launch_bounds__(256)
void transp_conv_kernel(const float* __restrict__ src, __bf16* __restrict__ dst, int K, int N) {
    __shared__ float t[32][33];
    int e = blockIdx.z;
    src += (size_t)e * K * N;
    dst += (size_t)e * K * N;
    int n0 = blockIdx.x*32, k0 = blockIdx.y*32;
    int tx = threadIdx.x & 31, ty = threadIdx.x >> 5;
    #pragma unroll
    for (int i = 0; i < 32; i += 8)
        t[ty+i][tx] = src[(size_t)(k0+ty+i)*N + n0 + tx];
    __syncthreads();
    #pragma unroll
    for (int i = 0; i < 32; i += 8)
        dst[(size_t)(n0+ty+i)*K + k0 + tx] = (__bf16)t[tx][ty+i];
}

// ---------------- bf16 MFMA GEMM: C[M,N] = A[M,K] * Bt[N,K]^T ----------------
// 128x128 tile, BK=64, 4 waves (2x2 of 64x64), 16x16x32 MFMA.
// EPI: 0=f32 out, 1=f32 out + residual R, 2=gelu->bf16 out, 3=bf16 out
template<int EPI>
__global__ __launch_bounds__(256)
void gemm_bf16_kernel(const __bf16* __restrict__ A, const __bf16* __restrict__ Bt,
                      const float* __restrict__ R, void* __restrict__ Cout,
                      int N, int K, long sA, long sB, long sC) {
    __shared__ __bf16 As[128*64];   // [row][k], 16B-granule XOR swizzle
    __shared__ __bf16 Bs[128*64];
    const int e = blockIdx.z;
    A  += (size_t)e * sA;
    Bt += (size_t)e * sB;
    const int m0 = blockIdx.y*128, n0 = blockIdx.x*128;
    const int tid = threadIdx.x;
    const int lane = tid & 63, w = tid >> 6;
    const int lr = lane & 15, lg = lane >> 4;
    const int wr = w >> 1, wc = w & 1;
    const int srow = tid >> 3, sc = tid & 7;
    f32x4 acc[4][4] = {};
    for (int k0 = 0; k0 < K; k0 += 64) {
        __syncthreads();
        #pragma unroll
        for (int i = 0; i < 4; ++i) {
            int row = srow + i*32;
            int lof = (row*128 + sc*16) ^ ((row&7)<<4);
            u32x4 va = *(const u32x4*)(A  + (size_t)(m0+row)*K + k0 + sc*8);
            *(u32x4*)((char*)As + lof) = va;
            u32x4 vb = *(const u32x4*)(Bt + (size_t)(n0+row)*K + k0 + sc*8);
            *(u32x4*)((char*)Bs + lof) = vb;
        }
        __syncthreads();
        #pragma unroll
        for (int ks = 0; ks < 2; ++ks) {
            bf16x8 af[4], bfr[4];
            #pragma unroll
            for (int mi = 0; mi < 4; ++mi) {
                int row = wr*64 + mi*16 + lr;
                af[mi] = *(const bf16x8*)((const char*)As + ((row*128 + (lg+4*ks)*16) ^ ((row&7)<<4)));
            }
            #pragma unroll
            for (int ni = 0; ni < 4; ++ni) {
                int row = wc*64 + ni*16 + lr;
                bfr[ni] = *(const bf16x8*)((const char*)Bs + ((row*128 + (lg+4*ks)*16) ^ ((row&7)<<4)));
            }
            #pragma unroll
            for (int mi = 0; mi < 4; ++mi)
                #pragma unroll
                for (int ni = 0; ni < 4; ++ni)
                    acc[mi][ni] = __builtin_amdgcn_mfma_f32_16x16x32_bf16(af[mi], bfr[ni], acc[mi][ni], 0,0,0);
        }
    }
    #pragma unroll
    for (int mi = 0; mi < 4; ++mi) {
        #pragma unroll
        for (int ni = 0; ni < 4; ++ni) {
            #pragma unroll
            for (int r = 0; r < 4; ++r) {
                int row = m0 + wr*64 + mi*16 + lg*4 + r;
                int col = n0 + wc*64 + ni*16 + lr;
                float v = acc[mi][ni][r];
                if (EPI == 1) v += R[(size_t)row*N + col];
                if (EPI == 2) {
                    float t = 0.7978845608028654f * (v + 0.044715f*v*v*v);
                    v = 0.5f * v * (1.f + tanhf(t));
                }
                if (EPI == 2 || EPI == 3)
                    ((__bf16*)Cout)[(size_t)e*sC + (size_t)row*N + col] = (__bf16)v;
                else
                    ((float*)Cout)[(size_t)e*sC + (size_t)row*N + col] = v;
            }
        }
    }
}

// ---------------- MFMA flash attention (bf16 qkv in, bf16 ao out) ----------------
__global__ __launch_bounds__(256)
void attn_mfma_kernel(const __bf16* __restrict__ qkv, __bf16* __restrict__ ao) {
    int q0 = blockIdx.x * 64;
    int h  = blockIdx.y;
    int hg = h >> 2, qi = h & 3;
    const int tid  = threadIdx.x;
    const int w    = tid >> 6;
    const int lane = tid & 63;
    const int lr   = lane & 15;
    const int lg   = lane >> 4;

    __shared__ __attribute__((aligned(16))) __bf16 Kls[64*64];
    __shared__ __attribute__((aligned(16))) __bf16 Vls[64*64];
    __shared__ __attribute__((aligned(16))) __bf16 Pls[4][16*64];

    int qrow = q0 + w*16 + lr;
    const __bf16* qp = qkv + (size_t)qrow*QKV_O + hg*384 + qi*64;
    bf16x8 qfrag[2];
    #pragma unroll
    for (int ks = 0; ks < 2; ++ks) {
        bf16x8 qr = *(const bf16x8*)(qp + ks*32 + lg*8);
        #pragma unroll
        for (int j = 0; j < 8; ++j) qfrag[ks][j] = (__bf16)((float)qr[j] * 0.125f);
    }

    f32x4 oacc[4] = {};
    float mrow[4] = {-INFINITY,-INFINITY,-INFINITY,-INFINITY};
    float lrow[4] = {0.f,0.f,0.f,0.f};

    int ntiles = q0/64 + 1;
    for (int t = 0; t < ntiles; ++t) {
        int kv0 = t*64;
        __syncthreads();
        #pragma unroll
        for (int i = 0; i < 2; ++i) {
            int g2 = tid + i*256;
            int row = g2 >> 3, c = g2 & 7;
            u32x4 v = *(const u32x4*)(qkv + (size_t)(kv0+row)*QKV_O + hg*384 + 256 + c*8);
            *(u32x4*)((char*)Kls + ((row*128 + c*16) ^ ((row&7)<<4))) = v;
        }
        {
            int p2 = tid & 31, dg = tid >> 5;
            const __bf16* v0p = qkv + (size_t)(kv0+2*p2)*QKV_O + hg*384 + 320 + dg*8;
            u16x8 a0 = *(const u16x8*)v0p;
            u16x8 a1 = *(const u16x8*)(v0p + QKV_O);
            #pragma unroll
            for (int j2 = 0; j2 < 8; ++j2) {
                int d = dg*8 + j2;
                u32 u = ((u32)a1[j2] << 16) | a0[j2];
                *(u32*)((char*)Vls + ((d*128 + p2*4) ^ ((d&7)<<4))) = u;
            }
        }
        __syncthreads();

        f32x4 sacc[4] = {};
        #pragma unroll
        for (int f = 0; f < 4; ++f) {
            int row = lr + 16*f;
            int swz = (row & 7) << 4;
            #pragma unroll
            for (int ks = 0; ks < 2; ++ks) {
                bf16x8 kf = *(const bf16x8*)((const char*)Kls + ((row*128 + (lg*8+32*ks)*2) ^ swz));
                sacc[f] = __builtin_amdgcn_mfma_f32_16x16x32_bf16(qfrag[ks], kf, sacc[f], 0,0,0);
            }
        }
        if (t == ntiles-1) {
            #pragma unroll
            for (int f = 0; f < 4; ++f)
                #pragma unroll
                for (int r = 0; r < 4; ++r)
                    if (lr + 16*f > 16*w + 4*lg + r) sacc[f][r] = -INFINITY;
        }
        float tm[4];
        #pragma unroll
        for (int r = 0; r < 4; ++r)
            tm[r] = fmaxf(fmaxf(sacc[0][r], sacc[1][r]), fmaxf(sacc[2][r], sacc[3][r]));
        #pragma unroll
        for (int msk = 1; msk < 16; msk <<= 1)
            #pragma unroll
            for (int r = 0; r < 4; ++r) tm[r] = fmaxf(tm[r], __shfl_xor(tm[r], msk, 64));
        float corr[4];
        #pragma unroll
        for (int r = 0; r < 4; ++r) {
            float mn = fmaxf(mrow[r], tm[r]);
            corr[r] = exp2f((mrow[r]-mn)*LOG2E);
            mrow[r] = mn;
        }
        float tl[4] = {0.f,0.f,0.f,0.f};
        #pragma unroll
        for (int f = 0; f < 4; ++f)
            #pragma unroll
            for (int r = 0; r < 4; ++r) {
                float p = exp2f((sacc[f][r]-mrow[r])*LOG2E);
                sacc[f][r] = p; tl[r] += p;
            }
        #pragma unroll
        for (int msk = 1; msk < 16; msk <<= 1)
            #pragma unroll
            for (int r = 0; r < 4; ++r) tl[r] += __shfl_xor(tl[r], msk, 64);
        #pragma unroll
        for (int r = 0; r < 4; ++r) lrow[r] = lrow[r]*corr[r] + tl[r];
        #pragma unroll
        for (int ct = 0; ct < 4; ++ct)
            #pragma unroll
            for (int r = 0; r < 4; ++r) oacc[ct][r] *= corr[r];
        #pragma unroll
        for (int f = 0; f < 4; ++f)
            #pragma unroll
            for (int r = 0; r < 4; ++r) {
                int row = 4*lg + r, col = lr + 16*f;
                *(__bf16*)((char*)&Pls[w][0] + ((row*128 + col*2) ^ ((row&7)<<4))) = (__bf16)sacc[f][r];
            }
        __syncthreads();
        bf16x8 pa[2];
        #pragma unroll
        for (int ks = 0; ks < 2; ++ks)
            pa[ks] = *(const bf16x8*)((const char*)&Pls[w][0] + ((lr*128 + (lg*8+32*ks)*2) ^ ((lr&7)<<4)));
        #pragma unroll
        for (int ct = 0; ct < 4; ++ct) {
            int row = lr + 16*ct;
            int swz = (row & 7) << 4;
            #pragma unroll
            for (int ks = 0; ks < 2; ++ks) {
                bf16x8 vf = *(const bf16x8*)((const char*)Vls + ((row*128 + (lg*8+32*ks)*2) ^ swz));
                oacc[ct] = __builtin_amdgcn_mfma_f32_16x16x32_bf16(pa[ks], vf, oacc[ct], 0,0,0);
            }
        }
    }
    #pragma unroll
    for (int ct = 0; ct < 4; ++ct)
        #pragma unroll
        for (int r = 0; r < 4; ++r) {
            int q = q0 + 16*w + 4*lg + r;
            ao[(size_t)q*HDIM + h*64 + 16*ct + lr] = (__bf16)(oacc[ct][r] / lrow[r]);
        }
}

// ---------------- Router (f32 exact) ----------------
__global__ __launch_bounds__(256)
void router_kernel(const float* __restrict__ x, const float* __restrict__ rw,
                   int* __restrict__ expi, float* __restrict__ expp) {
    int t = blockIdx.x, tid = threadIdx.x;
    __shared__ float red[256][8];
    float part[8] = {};
    const float* xr = x + (size_t)t*HDIM;
    for (int i = tid; i < HDIM; i += 256) {
        float xv = xr[i];
        const float* wp = rw + (size_t)i*NEXP;
        #pragma unroll
        for (int e2 = 0; e2 < 8; ++e2) part[e2] += xv * wp[e2];
    }
    #pragma unroll
    for (int e2 = 0; e2 < 8; ++e2) red[tid][e2] = part[e2];
    __syncthreads();
    for (int st = 128; st > 0; st >>= 1) {
        if (tid < st)
            #pragma unroll
            for (int e2 = 0; e2 < 8; ++e2) red[tid][e2] += red[tid+st][e2];
        __syncthreads();
    }
    if (tid == 0) {
        float lg[8];
        #pragma unroll
        for (int e2 = 0; e2 < 8; ++e2) lg[e2] = red[0][e2];
        int i0 = 0;
        for (int e2 = 1; e2 < 8; ++e2) if (lg[e2] > lg[i0]) i0 = e2;
        int i1 = -1;
        for (int e2 = 0; e2 < 8; ++e2) { if (e2 == i0) continue; if (i1 < 0 || lg[e2] > lg[i1]) i1 = e2; }
        float p1 = __expf(lg[i1] - lg[i0]);
        float inv = 1.f / (1.f + p1);
        expi[t*2]   = i0; expi[t*2+1] = i1;
        expp[t*2]   = inv; expp[t*2+1] = p1 * inv;
    }
}

// ---------------- Stable rank -> destination (single block, wave-scan) ----------------
__global__ __launch_bounds__(256)
void dst_fast_kernel(const int* __restrict__ expi, int* __restrict__ dst) {
    __shared__ int hist[256][9];    // pad 9 -> conflict-free tid-major access
    const int tid = threadIdx.x;
    int ev[16];
    #pragma unroll
    for (int i = 0; i < 16; i += 4)
        *(int4*)(ev+i) = *(const int4*)(expi + tid*16 + i);
    // per-thread histogram, static-indexed (avoid scratch)
    int cnt[8] = {};
    #pragma unroll
    for (int i = 0; i < 16; ++i)
        #pragma unroll
        for (int e = 0; e < 8; ++e) cnt[e] += (ev[i] == e);
    #pragma unroll
    for (int e = 0; e < 8; ++e) hist[tid][e] = cnt[e];
    __syncthreads();
    // exclusive prefix across threads, per expert; wave w handles experts w, w+4
    const int w = tid >> 6, lane = tid & 63;
    #pragma unroll
    for (int rep = 0; rep < 2; ++rep) {
        int e = w + rep*4;
        int h0 = hist[4*lane+0][e], h1 = hist[4*lane+1][e],
            h2 = hist[4*lane+2][e], h3 = hist[4*lane+3][e];
        int s = h0+h1+h2+h3, inc = s;
        #pragma unroll
        for (int off = 1; off < 64; off <<= 1) {
            int v = __shfl_up(inc, off, 64);
            if (lane >= off) inc += v;
        }
        int excl = inc - s;
        hist[4*lane+0][e] = excl;
        hist[4*lane+1][e] = excl + h0;
        hist[4*lane+2][e] = excl + h0 + h1;
        hist[4*lane+3][e] = excl + h0 + h1 + h2;
    }
    __syncthreads();
    int run[8];
    #pragma unroll
    for (int e = 0; e < 8; ++e) run[e] = hist[tid][e];
    int out[16];
    #pragma unroll
    for (int i = 0; i < 16; ++i) {
        int e = ev[i], within = 0;
        #pragma unroll
        for (int e2 = 0; e2 < 8; ++e2)
            if (e == e2) { within = run[e2]; run[e2]++; }
        out[i] = (within < CAP) ? (e*CAP + within) : -1;
    }
    #pragma unroll
    for (int i = 0; i < 16; i += 4)
        *(int4*)(dst + tid*16 + i) = *(const int4*)(out+i);
}

// ---------------- Scatter (f32 x -> bf16 xt) ----------------
__global__ void scatter_kernel(const float* __restrict__ x, const int* __restrict__ dst,
                               __bf16* __restrict__ xt) {
    int s = blockIdx.x;
    int d = dst[s];
    if (d < 0) return;
    int t = s >> 1;
    int i = threadIdx.x;
    float4 f = ((const float4*)(x + (size_t)t*HDIM))[i];
    __bf16* dp = xt + (size_t)d*HDIM + i*4;
    dp[0]=(__bf16)f.x; dp[1]=(__bf16)f.y; dp[2]=(__bf16)f.z; dp[3]=(__bf16)f.w;
}

// ---------------- Combine ----------------
__global__ void combine_kernel(const float* __restrict__ h1, const float* __restrict__ fc2,
                               const int* __restrict__ dst, const float* __restrict__ expp,
                               float* __restrict__ out) {
    int t = blockIdx.x;
    int d0 = dst[t*2], d1 = dst[t*2+1];
    float p0 = expp[t*2], p1 = expp[t*2+1];
    for (int i = threadIdx.x; i < HDIM; i += 256) {
        float v = h1[(size_t)t*HDIM + i];
        if (d0 >= 0) v += p0 * fc2[(size_t)d0*HDIM + i];
        if (d1 >= 0) v += p1 * fc2[(size_t)d1*HDIM + i];
        out[(size_t)t*HDIM + i] = v;
    }
}

extern "C" void kernel_launch(void* const* d_in, const int* in_sizes, int n_in,
                              void* d_out, int out_size, void* d_ws, size_t ws_size,
                              hipStream_t stream) {
    const float* hidden = (const float*)d_in[0];
    const float* ln1w   = (const float*)d_in[1];
    const float* ln1b_  = (const float*)d_in[2];
    const float* ln2w   = (const float*)d_in[3];
    const float* ln2b_  = (const float*)d_in[4];
    const float* qkvW   = (const float*)d_in[5];
    const float* projW  = (const float*)d_in[6];
    const float* routW  = (const float*)d_in[7];
    const float* w1     = (const float*)d_in[8];
    const float* w2     = (const float*)d_in[9];
    float* out = (float*)d_out;

    char* base = (char*)d_ws;
    __bf16* w1t    = (__bf16*)(base);                 // 33,554,432 B  [E][FDIM][HDIM]
    __bf16* w2t    = (__bf16*)(base + 33554432);      // 33,554,432 B  [E][HDIM][FDIM]
    __bf16* ln1b   = (__bf16*)(base + 0);             // 4 MB (aliases w1t span; dead before transpose)
    __bf16* qkvWb  = (__bf16*)(base + 4194304);
    __bf16* qkvb   = (__bf16*)(base + 7340032);
    __bf16* aob    = (__bf16*)(base + 13631488);
    __bf16* projWb = (__bf16*)(base + 17825792);
    char* B0 = base + 67108864;
    float*  h1   = (float*)(B0);
    __bf16* xtb  = (__bf16*)(B0 + 8388608);
    __bf16* fc1b = (__bf16*)(B0 + 18874368);
    float*  fc2  = (float*)(B0 + 39845888);
    float*  x2   = fc2;
    int*    expi = (int*)(B0 + 60817408);
    int*    dsts = (int*)(B0 + 60833792);
    float*  expp = (float*)(B0 + 60850176);

    ln_kernel<true><<<S_LEN, 256, 0, stream>>>(hidden, ln1w, ln1b_, ln1b);
    conv_bf16_kernel<<<(QKV_O*HDIM/8 + 255)/256, 256, 0, stream>>>(qkvW, qkvWb, QKV_O*HDIM/8);
    gemm_bf16_kernel<3><<<dim3(QKV_O/128, S_LEN/128, 1), 256, 0, stream>>>(
        ln1b, qkvWb, nullptr, qkvb, QKV_O, HDIM, 0, 0, 0);
    attn_mfma_kernel<<<dim3(S_LEN/64, NHEAD), 256, 0, stream>>>(qkvb, aob);
    conv_bf16_kernel<<<(HDIM*HDIM/8 + 255)/256, 256, 0, stream>>>(projW, projWb, HDIM*HDIM/8);
    gemm_bf16_kernel<1><<<dim3(HDIM/128, S_LEN/128, 1), 256, 0, stream>>>(
        aob, projWb, hidden, h1, HDIM, HDIM, 0, 0, 0);
    ln_kernel<false><<<S_LEN, 256, 0, stream>>>(h1, ln2w, ln2b_, x2);
    router_kernel<<<S_LEN, 256, 0, stream>>>(x2, routW, expi, expp);
    dst_fast_kernel<<<1, 256, 0, stream>>>(expi, dsts);
    hipMemsetAsync(xtb, 0, (size_t)TCAP * HDIM * sizeof(__bf16), stream);
    scatter_kernel<<<S_LEN*TOPK, 256, 0, stream>>>(x2, dsts, xtb);
    transp_conv_kernel<<<dim3(FDIM/32, HDIM/32, NEXP), 256, 0, stream>>>(w1, w1t, HDIM, FDIM);
    transp_conv_kernel<<<dim3(HDIM/32, FDIM/32, NEXP), 256, 0, stream>>>(w2, w2t, FDIM, HDIM);
    gemm_bf16_kernel<2><<<dim3(FDIM/128, CAP/128, NEXP), 256, 0, stream>>>(
        xtb, w1t, nullptr, fc1b, FDIM, HDIM,
        (long)CAP*HDIM, (long)FDIM*HDIM, (long)CAP*FDIM);
    gemm_bf16_kernel<0><<<dim3(HDIM/128, CAP/128, NEXP), 256, 0, stream>>>(
        fc1b, w2t, nullptr, fc2, HDIM, FDIM,
        (long)CAP*FDIM, (long)FDIM*HDIM, (long)CAP*HDIM);
    combine_kernel<<<S_LEN, 256, 0, stream>>>(h1, fc2, dsts, expp, out);
}

// Round 5
// 295.216 us; speedup vs baseline: 7.9462x; 1.0585x over previous
//
#include <hip/hip_runtime.h>
#include <hip/hip_bf16.h>
#include <stdint.h>

#define S_LEN 2048
#define HDIM  1024
#define NHEAD 16
#define NKVH  4
#define HEADD 64
#define QKV_O 1536   // NKV*(q_per_kv+2)*HD = 4*6*64
#define NEXP  8
#define TOPK  2
#define CAP   640    // ceil(2048*2/8*1.25)
#define TCAP  (NEXP*CAP)
#define FDIM  2048
#define LOG2E 1.44269504088896f

typedef __bf16 bf16x8 __attribute__((ext_vector_type(8)));
typedef float  f32x4  __attribute__((ext_vector_type(4)));
typedef unsigned int u32;
typedef u32 u32x4 __attribute__((ext_vector_type(4)));
typedef unsigned short u16;
typedef u16 u16x8 __attribute__((ext_vector_type(8)));

// ---------------- LayerNorm (templated output dtype) ----------------
template<bool BF>
__global__ void ln_kernel(const float* __restrict__ in, const float* __restrict__ w,
                          const float* __restrict__ b, void* __restrict__ outv) {
    int row = blockIdx.x;
    const float* x = in + (size_t)row * HDIM;
    __shared__ float red[256];
    int tid = threadIdx.x;
    float s = 0.f;
    for (int i = tid; i < HDIM; i += 256) s += x[i];
    red[tid] = s; __syncthreads();
    for (int st = 128; st > 0; st >>= 1) { if (tid < st) red[tid] += red[tid+st]; __syncthreads(); }
    float mu = red[0] / HDIM; __syncthreads();
    float v = 0.f;
    for (int i = tid; i < HDIM; i += 256) { float d = x[i]-mu; v += d*d; }
    red[tid] = v; __syncthreads();
    for (int st = 128; st > 0; st >>= 1) { if (tid < st) red[tid] += red[tid+st]; __syncthreads(); }
    float rstd = rsqrtf(red[0]/HDIM + 1e-5f);
    for (int i = tid; i < HDIM; i += 256) {
        float o = (x[i]-mu)*rstd*w[i] + b[i];
        if (BF) ((__bf16*)outv)[(size_t)row*HDIM + i] = (__bf16)o;
        else    ((float*)outv)[(size_t)row*HDIM + i] = o;
    }
}

// ---------------- f32 -> bf16 convert (n8 = count/8) ----------------
__global__ void conv_bf16_kernel(const float* __restrict__ src, __bf16* __restrict__ dst, int n8) {
    int i = blockIdx.x*256 + threadIdx.x;
    if (i >= n8) return;
    const float4* s = (const float4*)src + (size_t)i*2;
    float4 a = s[0], b = s[1];
    __bf16 tmp[8] = {(__bf16)a.x,(__bf16)a.y,(__bf16)a.z,(__bf16)a.w,
                     (__bf16)b.x,(__bf16)b.y,(__bf16)b.z,(__bf16)b.w};
    *(u32x4*)(dst + (size_t)i*8) = *(u32x4*)tmp;
}

// ---------------- transpose + convert: dst[e][n][k] = (bf16) src[e][k][n] ----------------
__global__ __launch_bounds__(256)
void transp_conv_kernel(const float* __restrict__ src, __bf16* __restrict__ dst, int K, int N) {
    __shared__ float t[32][33];
    int e = blockIdx.z;
    src += (size_t)e * K * N;
    dst += (size_t)e * K * N;
    int n0 = blockIdx.x*32, k0 = blockIdx.y*32;
    int tx = threadIdx.x & 31, ty = threadIdx.x >> 5;
    #pragma unroll
    for (int i = 0; i < 32; i += 8)
        t[ty+i][tx] = src[(size_t)(k0+ty+i)*N + n0 + tx];
    __syncthreads();
    #pragma unroll
    for (int i = 0; i < 32; i += 8)
        dst[(size_t)(n0+ty+i)*K + k0 + tx] = (__bf16)t[tx][ty+i];
}

// ---------------- bf16 MFMA GEMM: C[M,N] = A[M,K] * Bt[N,K]^T ----------------
template<int EPI>
__global__ __launch_bounds__(256)
void gemm_bf16_kernel(const __bf16* __restrict__ A, const __bf16* __restrict__ Bt,
                      const float* __restrict__ R, void* __restrict__ Cout,
                      int N, int K, long sA, long sB, long sC) {
    __shared__ __bf16 As[128*64];
    __shared__ __bf16 Bs[128*64];
    const int e = blockIdx.z;
    A  += (size_t)e * sA;
    Bt += (size_t)e * sB;
    const int m0 = blockIdx.y*128, n0 = blockIdx.x*128;
    const int tid = threadIdx.x;
    const int lane = tid & 63, w = tid >> 6;
    const int lr = lane & 15, lg = lane >> 4;
    const int wr = w >> 1, wc = w & 1;
    const int srow = tid >> 3, sc = tid & 7;
    f32x4 acc[4][4] = {};
    for (int k0 = 0; k0 < K; k0 += 64) {
        __syncthreads();
        #pragma unroll
        for (int i = 0; i < 4; ++i) {
            int row = srow + i*32;
            int lof = (row*128 + sc*16) ^ ((row&7)<<4);
            u32x4 va = *(const u32x4*)(A  + (size_t)(m0+row)*K + k0 + sc*8);
            *(u32x4*)((char*)As + lof) = va;
            u32x4 vb = *(const u32x4*)(Bt + (size_t)(n0+row)*K + k0 + sc*8);
            *(u32x4*)((char*)Bs + lof) = vb;
        }
        __syncthreads();
        #pragma unroll
        for (int ks = 0; ks < 2; ++ks) {
            bf16x8 af[4], bfr[4];
            #pragma unroll
            for (int mi = 0; mi < 4; ++mi) {
                int row = wr*64 + mi*16 + lr;
                af[mi] = *(const bf16x8*)((const char*)As + ((row*128 + (lg+4*ks)*16) ^ ((row&7)<<4)));
            }
            #pragma unroll
            for (int ni = 0; ni < 4; ++ni) {
                int row = wc*64 + ni*16 + lr;
                bfr[ni] = *(const bf16x8*)((const char*)Bs + ((row*128 + (lg+4*ks)*16) ^ ((row&7)<<4)));
            }
            #pragma unroll
            for (int mi = 0; mi < 4; ++mi)
                #pragma unroll
                for (int ni = 0; ni < 4; ++ni)
                    acc[mi][ni] = __builtin_amdgcn_mfma_f32_16x16x32_bf16(af[mi], bfr[ni], acc[mi][ni], 0,0,0);
        }
    }
    #pragma unroll
    for (int mi = 0; mi < 4; ++mi) {
        #pragma unroll
        for (int ni = 0; ni < 4; ++ni) {
            #pragma unroll
            for (int r = 0; r < 4; ++r) {
                int row = m0 + wr*64 + mi*16 + lg*4 + r;
                int col = n0 + wc*64 + ni*16 + lr;
                float v = acc[mi][ni][r];
                if (EPI == 1) v += R[(size_t)row*N + col];
                if (EPI == 2) {
                    float t = 0.7978845608028654f * (v + 0.044715f*v*v*v);
                    v = 0.5f * v * (1.f + tanhf(t));
                }
                if (EPI == 2 || EPI == 3)
                    ((__bf16*)Cout)[(size_t)e*sC + (size_t)row*N + col] = (__bf16)v;
                else
                    ((float*)Cout)[(size_t)e*sC + (size_t)row*N + col] = v;
            }
        }
    }
}

// ---------------- MFMA flash attention v3 ----------------
// grid (16, NH): block bx handles q-strips {bx, 31-bx} (uniform 17 KV-tiles each).
// KVBLK=128, double-buffered K/V with reg-prefetch (T14), 1 barrier per tile.
__global__ __launch_bounds__(256)
void attn_mfma_kernel(const __bf16* __restrict__ qkv, __bf16* __restrict__ ao) {
    const int bx = blockIdx.x;           // 0..15
    const int h  = blockIdx.y;
    const int hg = h >> 2, qi = h & 3;
    const int tid  = threadIdx.x;
    const int w    = tid >> 6;
    const int lane = tid & 63;
    const int lr   = lane & 15;
    const int lg   = lane >> 4;

    __shared__ __attribute__((aligned(16))) __bf16 Kls[2][128*64];   // [kv][d] swz
    __shared__ __attribute__((aligned(16))) __bf16 Vls[2][64*128];   // [d][kv] swz (V^T)
    __shared__ __attribute__((aligned(16))) __bf16 Pls[4][16*128];   // per-wave [q][kv] swz

    const int krow = tid >> 1, kc4 = (tid & 1) * 4;   // K staging coords
    const int va = tid & 31,  dg  = tid >> 5;         // V staging coords
    u32x4 kreg[4]; u16x8 vreg[4];

    const __bf16* kbase = qkv + hg*384 + 256;
    const __bf16* vbase = qkv + hg*384 + 320;

#define ISSUE(T) do { \
        const __bf16* kp = kbase + (size_t)((T)*128 + krow)*QKV_O; \
        kreg[0] = *(const u32x4*)(kp + (kc4+0)*8); \
        kreg[1] = *(const u32x4*)(kp + (kc4+1)*8); \
        kreg[2] = *(const u32x4*)(kp + (kc4+2)*8); \
        kreg[3] = *(const u32x4*)(kp + (kc4+3)*8); \
        const __bf16* vp = vbase + (size_t)((T)*128 + 4*va)*QKV_O + dg*8; \
        vreg[0] = *(const u16x8*)(vp); \
        vreg[1] = *(const u16x8*)(vp + QKV_O); \
        vreg[2] = *(const u16x8*)(vp + 2*QKV_O); \
        vreg[3] = *(const u16x8*)(vp + 3*QKV_O); \
    } while(0)

#define COMMIT(B) do { \
        char* Kb = (char*)Kls[B]; \
        _Pragma("unroll") \
        for (int i = 0; i < 4; ++i) \
            *(u32x4*)(Kb + ((krow*128 + (kc4+i)*16) ^ ((krow&7)<<4))) = kreg[i]; \
        char* Vb = (char*)Vls[B]; \
        _Pragma("unroll") \
        for (int j = 0; j < 8; ++j) { \
            int d = dg*8 + j; \
            u32 u01 = ((u32)vreg[1][j] << 16) | vreg[0][j]; \
            u32 u23 = ((u32)vreg[3][j] << 16) | vreg[2][j]; \
            int vb0 = d*256 + va*8; \
            *(u32*)(Vb + ((vb0    ) ^ ((d&7)<<4))) = u01; \
            *(u32*)(Vb + ((vb0 + 4) ^ ((d&7)<<4))) = u23; \
        } \
    } while(0)

    for (int s = 0; s < 2; ++s) {
        const int qb = s ? (31 - bx) : bx;
        const int q0 = qb * 64;
        const int ntiles = (qb >> 1) + 1;   // KVBLK=128 tiles covering [0, q0+64)

        // Q fragments (scaled by 1/8)
        const int qrow = q0 + w*16 + lr;
        const __bf16* qp = qkv + (size_t)qrow*QKV_O + hg*384 + qi*64;
        bf16x8 qfrag[2];
        #pragma unroll
        for (int ks = 0; ks < 2; ++ks) {
            bf16x8 qr = *(const bf16x8*)(qp + ks*32 + lg*8);
            #pragma unroll
            for (int j = 0; j < 8; ++j) qfrag[ks][j] = (__bf16)((float)qr[j] * 0.125f);
        }

        f32x4 oacc[4] = {};
        float mrow[4] = {-INFINITY,-INFINITY,-INFINITY,-INFINITY};
        float lrow[4] = {0.f,0.f,0.f,0.f};

        ISSUE(0);
        __syncthreads();      // strip boundary: prior buffer readers done
        COMMIT(0);
        __syncthreads();

        for (int t = 0; t < ntiles; ++t) {
            const int cur = t & 1;
            const bool more = (t+1 < ntiles);
            if (more) ISSUE(t+1);          // prefetch next tile into regs (T14)

            // ---- S = Q K^T  (8 kv col-tiles x 2 k-steps)
            f32x4 sacc[8] = {};
            const char* Kb = (const char*)Kls[cur];
            #pragma unroll
            for (int f = 0; f < 8; ++f) {
                int row = lr + 16*f;
                int swz = (row & 7) << 4;
                #pragma unroll
                for (int ks = 0; ks < 2; ++ks) {
                    bf16x8 kf = *(const bf16x8*)(Kb + ((row*128 + (lg*8+32*ks)*2) ^ swz));
                    sacc[f] = __builtin_amdgcn_mfma_f32_16x16x32_bf16(qfrag[ks], kf, sacc[f], 0,0,0);
                }
            }
            // ---- causal mask (only last tile reaches/passes the diagonal)
            if (t == ntiles-1) {
                int koff = t*128 - q0;    // kv_local - q_local offset
                #pragma unroll
                for (int f = 0; f < 8; ++f)
                    #pragma unroll
                    for (int r = 0; r < 4; ++r)
                        if (koff + lr + 16*f > 16*w + 4*lg + r) sacc[f][r] = -INFINITY;
            }
            // ---- online softmax (rows r: q = 4*lg+r; reduce over 16 lr lanes)
            float tm[4];
            #pragma unroll
            for (int r = 0; r < 4; ++r) {
                float a = fmaxf(fmaxf(sacc[0][r], sacc[1][r]), fmaxf(sacc[2][r], sacc[3][r]));
                float b2 = fmaxf(fmaxf(sacc[4][r], sacc[5][r]), fmaxf(sacc[6][r], sacc[7][r]));
                tm[r] = fmaxf(a, b2);
            }
            #pragma unroll
            for (int msk = 1; msk < 16; msk <<= 1)
                #pragma unroll
                for (int r = 0; r < 4; ++r) tm[r] = fmaxf(tm[r], __shfl_xor(tm[r], msk, 64));
            float corr[4];
            #pragma unroll
            for (int r = 0; r < 4; ++r) {
                float mn = fmaxf(mrow[r], tm[r]);
                corr[r] = exp2f((mrow[r]-mn)*LOG2E);
                mrow[r] = mn;
            }
            float tl[4] = {0.f,0.f,0.f,0.f};
            #pragma unroll
            for (int f = 0; f < 8; ++f)
                #pragma unroll
                for (int r = 0; r < 4; ++r) {
                    float p = exp2f((sacc[f][r]-mrow[r])*LOG2E);
                    sacc[f][r] = p; tl[r] += p;
                }
            #pragma unroll
            for (int msk = 1; msk < 16; msk <<= 1)
                #pragma unroll
                for (int r = 0; r < 4; ++r) tl[r] += __shfl_xor(tl[r], msk, 64);
            #pragma unroll
            for (int r = 0; r < 4; ++r) lrow[r] = lrow[r]*corr[r] + tl[r];
            #pragma unroll
            for (int ct = 0; ct < 4; ++ct)
                #pragma unroll
                for (int r = 0; r < 4; ++r) oacc[ct][r] *= corr[r];
            // ---- P -> per-wave LDS (no cross-wave barrier needed)
            char* Pw = (char*)&Pls[w][0];
            #pragma unroll
            for (int f = 0; f < 8; ++f)
                #pragma unroll
                for (int r = 0; r < 4; ++r) {
                    int row = 4*lg + r, col = lr + 16*f;
                    *(__bf16*)(Pw + ((row*256 + col*2) ^ ((row&7)<<4))) = (__bf16)sacc[f][r];
                }
            // ---- O += P V  (4 d-tiles x 4 k-steps)
            const char* Vb = (const char*)Vls[cur];
            bf16x8 pa[4];
            #pragma unroll
            for (int ks = 0; ks < 4; ++ks)
                pa[ks] = *(const bf16x8*)(Pw + ((lr*256 + (lg*8+32*ks)*2) ^ ((lr&7)<<4)));
            #pragma unroll
            for (int ct = 0; ct < 4; ++ct) {
                int row = lr + 16*ct;
                int swz = (row & 7) << 4;
                #pragma unroll
                for (int ks = 0; ks < 4; ++ks) {
                    bf16x8 vf = *(const bf16x8*)(Vb + ((row*256 + (lg*8+32*ks)*2) ^ swz));
                    oacc[ct] = __builtin_amdgcn_mfma_f32_16x16x32_bf16(pa[ks], vf, oacc[ct], 0,0,0);
                }
            }
            if (more) { COMMIT(cur^1); __syncthreads(); }   // single barrier per tile
        }
        // ---- epilogue
        #pragma unroll
        for (int ct = 0; ct < 4; ++ct)
            #pragma unroll
            for (int r = 0; r < 4; ++r) {
                int q = q0 + 16*w + 4*lg + r;
                ao[(size_t)q*HDIM + h*64 + 16*ct + lr] = (__bf16)(oacc[ct][r] / lrow[r]);
            }
    }
#undef ISSUE
#undef COMMIT
}

// ---------------- Router (f32 exact) ----------------
__global__ __launch_bounds__(256)
void router_kernel(const float* __restrict__ x, const float* __restrict__ rw,
                   int* __restrict__ expi, float* __restrict__ expp) {
    int t = blockIdx.x, tid = threadIdx.x;
    __shared__ float red[256][8];
    float part[8] = {};
    const float* xr = x + (size_t)t*HDIM;
    for (int i = tid; i < HDIM; i += 256) {
        float xv = xr[i];
        const float* wp = rw + (size_t)i*NEXP;
        #pragma unroll
        for (int e2 = 0; e2 < 8; ++e2) part[e2] += xv * wp[e2];
    }
    #pragma unroll
    for (int e2 = 0; e2 < 8; ++e2) red[tid][e2] = part[e2];
    __syncthreads();
    for (int st = 128; st > 0; st >>= 1) {
        if (tid < st)
            #pragma unroll
            for (int e2 = 0; e2 < 8; ++e2) red[tid][e2] += red[tid+st][e2];
        __syncthreads();
    }
    if (tid == 0) {
        float lg[8];
        #pragma unroll
        for (int e2 = 0; e2 < 8; ++e2) lg[e2] = red[0][e2];
        int i0 = 0;
        for (int e2 = 1; e2 < 8; ++e2) if (lg[e2] > lg[i0]) i0 = e2;
        int i1 = -1;
        for (int e2 = 0; e2 < 8; ++e2) { if (e2 == i0) continue; if (i1 < 0 || lg[e2] > lg[i1]) i1 = e2; }
        float p1 = __expf(lg[i1] - lg[i0]);
        float inv = 1.f / (1.f + p1);
        expi[t*2]   = i0; expi[t*2+1] = i1;
        expp[t*2]   = inv; expp[t*2+1] = p1 * inv;
    }
}

// ---------------- Stable rank -> destination (single block, wave-scan) ----------------
__global__ __launch_bounds__(256)
void dst_fast_kernel(const int* __restrict__ expi, int* __restrict__ dst) {
    __shared__ int hist[256][9];
    const int tid = threadIdx.x;
    int ev[16];
    #pragma unroll
    for (int i = 0; i < 16; i += 4)
        *(int4*)(ev+i) = *(const int4*)(expi + tid*16 + i);
    int cnt[8] = {};
    #pragma unroll
    for (int i = 0; i < 16; ++i)
        #pragma unroll
        for (int e = 0; e < 8; ++e) cnt[e] += (ev[i] == e);
    #pragma unroll
    for (int e = 0; e < 8; ++e) hist[tid][e] = cnt[e];
    __syncthreads();
    const int w = tid >> 6, lane = tid & 63;
    #pragma unroll
    for (int rep = 0; rep < 2; ++rep) {
        int e = w + rep*4;
        int h0 = hist[4*lane+0][e], h1 = hist[4*lane+1][e],
            h2 = hist[4*lane+2][e], h3 = hist[4*lane+3][e];
        int s = h0+h1+h2+h3, inc = s;
        #pragma unroll
        for (int off = 1; off < 64; off <<= 1) {
            int v = __shfl_up(inc, off, 64);
            if (lane >= off) inc += v;
        }
        int excl = inc - s;
        hist[4*lane+0][e] = excl;
        hist[4*lane+1][e] = excl + h0;
        hist[4*lane+2][e] = excl + h0 + h1;
        hist[4*lane+3][e] = excl + h0 + h1 + h2;
    }
    __syncthreads();
    int run[8];
    #pragma unroll
    for (int e = 0; e < 8; ++e) run[e] = hist[tid][e];
    int out[16];
    #pragma unroll
    for (int i = 0; i < 16; ++i) {
        int e = ev[i], within = 0;
        #pragma unroll
        for (int e2 = 0; e2 < 8; ++e2)
            if (e == e2) { within = run[e2]; run[e2]++; }
        out[i] = (within < CAP) ? (e*CAP + within) : -1;
    }
    #pragma unroll
    for (int i = 0; i < 16; i += 4)
        *(int4*)(dst + tid*16 + i) = *(const int4*)(out+i);
}

// ---------------- Scatter (f32 x -> bf16 xt) ----------------
__global__ void scatter_kernel(const float* __restrict__ x, const int* __restrict__ dst,
                               __bf16* __restrict__ xt) {
    int s = blockIdx.x;
    int d = dst[s];
    if (d < 0) return;
    int t = s >> 1;
    int i = threadIdx.x;
    float4 f = ((const float4*)(x + (size_t)t*HDIM))[i];
    __bf16* dp = xt + (size_t)d*HDIM + i*4;
    dp[0]=(__bf16)f.x; dp[1]=(__bf16)f.y; dp[2]=(__bf16)f.z; dp[3]=(__bf16)f.w;
}

// ---------------- Combine ----------------
__global__ void combine_kernel(const float* __restrict__ h1, const float* __restrict__ fc2,
                               const int* __restrict__ dst, const float* __restrict__ expp,
                               float* __restrict__ out) {
    int t = blockIdx.x;
    int d0 = dst[t*2], d1 = dst[t*2+1];
    float p0 = expp[t*2], p1 = expp[t*2+1];
    for (int i = threadIdx.x; i < HDIM; i += 256) {
        float v = h1[(size_t)t*HDIM + i];
        if (d0 >= 0) v += p0 * fc2[(size_t)d0*HDIM + i];
        if (d1 >= 0) v += p1 * fc2[(size_t)d1*HDIM + i];
        out[(size_t)t*HDIM + i] = v;
    }
}

extern "C" void kernel_launch(void* const* d_in, const int* in_sizes, int n_in,
                              void* d_out, int out_size, void* d_ws, size_t ws_size,
                              hipStream_t stream) {
    const float* hidden = (const float*)d_in[0];
    const float* ln1w   = (const float*)d_in[1];
    const float* ln1b_  = (const float*)d_in[2];
    const float* ln2w   = (const float*)d_in[3];
    const float* ln2b_  = (const float*)d_in[4];
    const float* qkvW   = (const float*)d_in[5];
    const float* projW  = (const float*)d_in[6];
    const float* routW  = (const float*)d_in[7];
    const float* w1     = (const float*)d_in[8];
    const float* w2     = (const float*)d_in[9];
    float* out = (float*)d_out;

    char* base = (char*)d_ws;
    __bf16* w1t    = (__bf16*)(base);                 // [E][FDIM][HDIM]
    __bf16* w2t    = (__bf16*)(base + 33554432);      // [E][HDIM][FDIM]
    __bf16* ln1b   = (__bf16*)(base + 0);             // aliases w1t span; dead before transpose
    __bf16* qkvWb  = (__bf16*)(base + 4194304);
    __bf16* qkvb   = (__bf16*)(base + 7340032);
    __bf16* aob    = (__bf16*)(base + 13631488);
    __bf16* projWb = (__bf16*)(base + 17825792);
    char* B0 = base + 67108864;
    float*  h1   = (float*)(B0);
    __bf16* xtb  = (__bf16*)(B0 + 8388608);
    __bf16* fc1b = (__bf16*)(B0 + 18874368);
    float*  fc2  = (float*)(B0 + 39845888);
    float*  x2   = fc2;
    int*    expi = (int*)(B0 + 60817408);
    int*    dsts = (int*)(B0 + 60833792);
    float*  expp = (float*)(B0 + 60850176);

    ln_kernel<true><<<S_LEN, 256, 0, stream>>>(hidden, ln1w, ln1b_, ln1b);
    conv_bf16_kernel<<<(QKV_O*HDIM/8 + 255)/256, 256, 0, stream>>>(qkvW, qkvWb, QKV_O*HDIM/8);
    gemm_bf16_kernel<3><<<dim3(QKV_O/128, S_LEN/128, 1), 256, 0, stream>>>(
        ln1b, qkvWb, nullptr, qkvb, QKV_O, HDIM, 0, 0, 0);
    attn_mfma_kernel<<<dim3(16, NHEAD), 256, 0, stream>>>(qkvb, aob);
    conv_bf16_kernel<<<(HDIM*HDIM/8 + 255)/256, 256, 0, stream>>>(projW, projWb, HDIM*HDIM/8);
    gemm_bf16_kernel<1><<<dim3(HDIM/128, S_LEN/128, 1), 256, 0, stream>>>(
        aob, projWb, hidden, h1, HDIM, HDIM, 0, 0, 0);
    ln_kernel<false><<<S_LEN, 256, 0, stream>>>(h1, ln2w, ln2b_, x2);
    router_kernel<<<S_LEN, 256, 0, stream>>>(x2, routW, expi, expp);
    dst_fast_kernel<<<1, 256, 0, stream>>>(expi, dsts);
    hipMemsetAsync(xtb, 0, (size_t)TCAP * HDIM * sizeof(__bf16), stream);
    scatter_kernel<<<S_LEN*TOPK, 256, 0, stream>>>(x2, dsts, xtb);
    transp_conv_kernel<<<dim3(FDIM/32, HDIM/32, NEXP), 256, 0, stream>>>(w1, w1t, HDIM, FDIM);
    transp_conv_kernel<<<dim3(HDIM/32, FDIM/32, NEXP), 256, 0, stream>>>(w2, w2t, FDIM, HDIM);
    gemm_bf16_kernel<2><<<dim3(FDIM/128, CAP/128, NEXP), 256, 0, stream>>>(
        xtb, w1t, nullptr, fc1b, FDIM, HDIM,
        (long)CAP*HDIM, (long)FDIM*HDIM, (long)CAP*FDIM);
    gemm_bf16_kernel<0><<<dim3(HDIM/128, CAP/128, NEXP), 256, 0, stream>>>(
        fc1b, w2t, nullptr, fc2, HDIM, FDIM,
        (long)CAP*FDIM, (long)FDIM*HDIM, (long)CAP*HDIM);
    combine_kernel<<<S_LEN, 256, 0, stream>>>(h1, fc2, dsts, expp, out);
}

// Round 6
// 278.273 us; speedup vs baseline: 8.4300x; 1.0609x over previous
//
#include <hip/hip_runtime.h>
#include <hip/hip_bf16.h>
#include <stdint.h>

#define S_LEN 2048
#define HDIM  1024
#define NHEAD 16
#define NKVH  4
#define HEADD 64
#define QKV_O 1536   // NKV*(q_per_kv+2)*HD = 4*6*64
#define NEXP  8
#define TOPK  2
#define CAP   640    // ceil(2048*2/8*1.25)
#define TCAP  (NEXP*CAP)
#define FDIM  2048
#define LOG2E 1.44269504088896f

typedef __bf16 bf16x8 __attribute__((ext_vector_type(8)));
typedef float  f32x4  __attribute__((ext_vector_type(4)));
typedef unsigned int u32;
typedef u32 u32x4 __attribute__((ext_vector_type(4)));
typedef unsigned short u16;
typedef u16 u16x8 __attribute__((ext_vector_type(8)));

// async global->LDS, 16B per lane; LDS dest is wave-uniform base + lane*16
__device__ __forceinline__ void gload16(const __bf16* g, __bf16* l) {
    __builtin_amdgcn_global_load_lds(
        (const __attribute__((address_space(1))) u32*)g,
        (__attribute__((address_space(3))) u32*)l, 16, 0, 0);
}

// ---------------- LayerNorm (templated output dtype) ----------------
template<bool BF>
__global__ void ln_kernel(const float* __restrict__ in, const float* __restrict__ w,
                          const float* __restrict__ b, void* __restrict__ outv) {
    int row = blockIdx.x;
    const float* x = in + (size_t)row * HDIM;
    __shared__ float red[256];
    int tid = threadIdx.x;
    float s = 0.f;
    for (int i = tid; i < HDIM; i += 256) s += x[i];
    red[tid] = s; __syncthreads();
    for (int st = 128; st > 0; st >>= 1) { if (tid < st) red[tid] += red[tid+st]; __syncthreads(); }
    float mu = red[0] / HDIM; __syncthreads();
    float v = 0.f;
    for (int i = tid; i < HDIM; i += 256) { float d = x[i]-mu; v += d*d; }
    red[tid] = v; __syncthreads();
    for (int st = 128; st > 0; st >>= 1) { if (tid < st) red[tid] += red[tid+st]; __syncthreads(); }
    float rstd = rsqrtf(red[0]/HDIM + 1e-5f);
    for (int i = tid; i < HDIM; i += 256) {
        float o = (x[i]-mu)*rstd*w[i] + b[i];
        if (BF) ((__bf16*)outv)[(size_t)row*HDIM + i] = (__bf16)o;
        else    ((float*)outv)[(size_t)row*HDIM + i] = o;
    }
}

// ---------------- f32 -> bf16 convert (n8 = count/8) ----------------
__global__ void conv_bf16_kernel(const float* __restrict__ src, __bf16* __restrict__ dst, int n8) {
    int i = blockIdx.x*256 + threadIdx.x;
    if (i >= n8) return;
    const float4* s = (const float4*)src + (size_t)i*2;
    float4 a = s[0], b = s[1];
    __bf16 tmp[8] = {(__bf16)a.x,(__bf16)a.y,(__bf16)a.z,(__bf16)a.w,
                     (__bf16)b.x,(__bf16)b.y,(__bf16)b.z,(__bf16)b.w};
    *(u32x4*)(dst + (size_t)i*8) = *(u32x4*)tmp;
}

// ---------------- transpose + convert: dst[e][n][k] = (bf16) src[e][k][n] ----------------
__global__ __launch_bounds__(256)
void transp_conv_kernel(const float* __restrict__ src, __bf16* __restrict__ dst, int K, int N) {
    __shared__ float t[32][33];
    int e = blockIdx.z;
    src += (size_t)e * K * N;
    dst += (size_t)e * K * N;
    int n0 = blockIdx.x*32, k0 = blockIdx.y*32;
    int tx = threadIdx.x & 31, ty = threadIdx.x >> 5;
    #pragma unroll
    for (int i = 0; i < 32; i += 8)
        t[ty+i][tx] = src[(size_t)(k0+ty+i)*N + n0 + tx];
    __syncthreads();
    #pragma unroll
    for (int i = 0; i < 32; i += 8)
        dst[(size_t)(n0+ty+i)*K + k0 + tx] = (__bf16)t[tx][ty+i];
}

// ---------------- bf16 MFMA GEMM (m97 structure): C[M,N] = A[M,K] * Bt[N,K]^T ----------------
// 128x128 tile, BK=64, global_load_lds staging: linear LDS dest, source granule
// pre-swizzled by g^(row&7); swizzled ds_read undoes it (involution).
template<int EPI>
__global__ __launch_bounds__(256)
void gemm_bf16_kernel(const __bf16* __restrict__ A, const __bf16* __restrict__ Bt,
                      const float* __restrict__ R, void* __restrict__ Cout,
                      int N, int K, long sA, long sB, long sC) {
    __shared__ __bf16 As[128*64];
    __shared__ __bf16 Bs[128*64];
    const int e = blockIdx.z;
    A  += (size_t)e * sA;
    Bt += (size_t)e * sB;
    const int m0 = blockIdx.y*128, n0 = blockIdx.x*128;
    const int tid = threadIdx.x;
    const int lane = tid & 63, w = tid >> 6;
    const int lr = lane & 15, lg = lane >> 4;
    const int wr = w >> 1, wc = w & 1;
    const int srow8 = lane >> 3, sg = lane & 7;    // staging lane coords
    f32x4 acc[4][4] = {};
    for (int k0 = 0; k0 < K; k0 += 64) {
        __syncthreads();
        #pragma unroll
        for (int i = 0; i < 4; ++i) {
            int row = 32*w + 8*i + srow8;
            int src_g = sg ^ (row & 7);
            gload16(A  + (size_t)(m0+row)*K + k0 + src_g*8,
                    (__bf16*)((char*)As + (32*w + 8*i)*128));
            gload16(Bt + (size_t)(n0+row)*K + k0 + src_g*8,
                    (__bf16*)((char*)Bs + (32*w + 8*i)*128));
        }
        __syncthreads();
        #pragma unroll
        for (int ks = 0; ks < 2; ++ks) {
            bf16x8 af[4], bfr[4];
            #pragma unroll
            for (int mi = 0; mi < 4; ++mi) {
                int row = wr*64 + mi*16 + lr;
                af[mi] = *(const bf16x8*)((const char*)As + ((row*128 + (lg+4*ks)*16) ^ ((row&7)<<4)));
            }
            #pragma unroll
            for (int ni = 0; ni < 4; ++ni) {
                int row = wc*64 + ni*16 + lr;
                bfr[ni] = *(const bf16x8*)((const char*)Bs + ((row*128 + (lg+4*ks)*16) ^ ((row&7)<<4)));
            }
            #pragma unroll
            for (int mi = 0; mi < 4; ++mi)
                #pragma unroll
                for (int ni = 0; ni < 4; ++ni)
                    acc[mi][ni] = __builtin_amdgcn_mfma_f32_16x16x32_bf16(af[mi], bfr[ni], acc[mi][ni], 0,0,0);
        }
    }
    #pragma unroll
    for (int mi = 0; mi < 4; ++mi) {
        #pragma unroll
        for (int ni = 0; ni < 4; ++ni) {
            #pragma unroll
            for (int r = 0; r < 4; ++r) {
                int row = m0 + wr*64 + mi*16 + lg*4 + r;
                int col = n0 + wc*64 + ni*16 + lr;
                float v = acc[mi][ni][r];
                if (EPI == 1) v += R[(size_t)row*N + col];
                if (EPI == 2) {
                    float t = 0.7978845608028654f * (v + 0.044715f*v*v*v);
                    v = 0.5f * v * (1.f + tanhf(t));
                }
                if (EPI == 2 || EPI == 3)
                    ((__bf16*)Cout)[(size_t)e*sC + (size_t)row*N + col] = (__bf16)v;
                else
                    ((float*)Cout)[(size_t)e*sC + (size_t)row*N + col] = v;
            }
        }
    }
}

// ---------------- MFMA flash attention v4: 8 waves, 128-row Q strips ----------------
// grid (16, NH), 512 threads. Block bx handles strips {bx, 15-bx} (exactly 17 KV tiles).
// KVBLK=128, double-buffered K/V with reg-prefetch, 1 barrier per tile.
__global__ __launch_bounds__(512)
void attn_mfma_kernel(const __bf16* __restrict__ qkv, __bf16* __restrict__ ao) {
    const int bx = blockIdx.x;           // 0..15
    const int h  = blockIdx.y;
    const int hg = h >> 2, qi = h & 3;
    const int tid  = threadIdx.x;        // 0..511
    const int w    = tid >> 6;           // 0..7
    const int lane = tid & 63;
    const int lr   = lane & 15;
    const int lg   = lane >> 4;

    __shared__ __attribute__((aligned(16))) __bf16 Kls[2][128*64];   // [kv][d] swz
    __shared__ __attribute__((aligned(16))) __bf16 Vls[2][64*128];   // [d][kv] swz (V^T)
    __shared__ __attribute__((aligned(16))) __bf16 Pls[8][16*128];   // per-wave [q][kv] swz

    const int krow = tid >> 2, kc = (tid & 3) * 2;    // K staging: 2 granules/thread
    const int va = tid & 63,  dg  = tid >> 6;         // V staging: kv pair 2*va, d's dg*8..+8
    u32x4 kreg[2]; u16x8 vreg[2];

    const __bf16* kbase = qkv + hg*384 + 256;
    const __bf16* vbase = qkv + hg*384 + 320;

#define ISSUE(T) do { \
        const __bf16* kp = kbase + (size_t)((T)*128 + krow)*QKV_O + kc*8; \
        kreg[0] = *(const u32x4*)(kp); \
        kreg[1] = *(const u32x4*)(kp + 8); \
        const __bf16* vp = vbase + (size_t)((T)*128 + 2*va)*QKV_O + dg*8; \
        vreg[0] = *(const u16x8*)(vp); \
        vreg[1] = *(const u16x8*)(vp + QKV_O); \
    } while(0)

#define COMMIT(B) do { \
        char* Kb = (char*)Kls[B]; \
        *(u32x4*)(Kb + ((krow*128 + (kc+0)*16) ^ ((krow&7)<<4))) = kreg[0]; \
        *(u32x4*)(Kb + ((krow*128 + (kc+1)*16) ^ ((krow&7)<<4))) = kreg[1]; \
        char* Vb = (char*)Vls[B]; \
        _Pragma("unroll") \
        for (int j = 0; j < 8; ++j) { \
            int d = dg*8 + j; \
            u32 u = ((u32)vreg[1][j] << 16) | vreg[0][j]; \
            *(u32*)(Vb + ((d*256 + va*4) ^ ((d&7)<<4))) = u; \
        } \
    } while(0)

    for (int s = 0; s < 2; ++s) {
        const int qb = s ? (15 - bx) : bx;
        const int q0 = qb * 128;
        const int ntiles = qb + 1;

        // Q fragments (scaled by 1/8); wave w owns q rows [q0+16w, +16)
        const int qrow = q0 + w*16 + lr;
        const __bf16* qp = qkv + (size_t)qrow*QKV_O + hg*384 + qi*64;
        bf16x8 qfrag[2];
        #pragma unroll
        for (int ks = 0; ks < 2; ++ks) {
            bf16x8 qr = *(const bf16x8*)(qp + ks*32 + lg*8);
            #pragma unroll
            for (int j = 0; j < 8; ++j) qfrag[ks][j] = (__bf16)((float)qr[j] * 0.125f);
        }

        f32x4 oacc[4] = {};
        float mrow[4] = {-INFINITY,-INFINITY,-INFINITY,-INFINITY};
        float lrow[4] = {0.f,0.f,0.f,0.f};

        ISSUE(0);
        __syncthreads();      // strip boundary: prior buffer readers done
        COMMIT(0);
        __syncthreads();

        for (int t = 0; t < ntiles; ++t) {
            const int cur = t & 1;
            const bool more = (t+1 < ntiles);
            if (more) ISSUE(t+1);          // prefetch next tile into regs

            // ---- S = Q K^T  (8 kv col-tiles x 2 k-steps)
            f32x4 sacc[8] = {};
            const char* Kb = (const char*)Kls[cur];
            #pragma unroll
            for (int f = 0; f < 8; ++f) {
                int row = lr + 16*f;
                int swz = (row & 7) << 4;
                #pragma unroll
                for (int ks = 0; ks < 2; ++ks) {
                    bf16x8 kf = *(const bf16x8*)(Kb + ((row*128 + (lg*8+32*ks)*2) ^ swz));
                    sacc[f] = __builtin_amdgcn_mfma_f32_16x16x32_bf16(qfrag[ks], kf, sacc[f], 0,0,0);
                }
            }
            // ---- causal mask (only the last tile touches the diagonal)
            if (t == ntiles-1) {
                #pragma unroll
                for (int f = 0; f < 8; ++f)
                    #pragma unroll
                    for (int r = 0; r < 4; ++r)
                        if (lr + 16*f > 16*w + 4*lg + r) sacc[f][r] = -INFINITY;
            }
            // ---- online softmax (rows r: q = 16w+4lg+r; reduce over 16 lr lanes)
            float tm[4];
            #pragma unroll
            for (int r = 0; r < 4; ++r) {
                float a = fmaxf(fmaxf(sacc[0][r], sacc[1][r]), fmaxf(sacc[2][r], sacc[3][r]));
                float b2 = fmaxf(fmaxf(sacc[4][r], sacc[5][r]), fmaxf(sacc[6][r], sacc[7][r]));
                tm[r] = fmaxf(a, b2);
            }
            #pragma unroll
            for (int msk = 1; msk < 16; msk <<= 1)
                #pragma unroll
                for (int r = 0; r < 4; ++r) tm[r] = fmaxf(tm[r], __shfl_xor(tm[r], msk, 64));
            float corr[4];
            #pragma unroll
            for (int r = 0; r < 4; ++r) {
                float mn = fmaxf(mrow[r], tm[r]);
                corr[r] = exp2f((mrow[r]-mn)*LOG2E);
                mrow[r] = mn;
            }
            float tl[4] = {0.f,0.f,0.f,0.f};
            #pragma unroll
            for (int f = 0; f < 8; ++f)
                #pragma unroll
                for (int r = 0; r < 4; ++r) {
                    float p = exp2f((sacc[f][r]-mrow[r])*LOG2E);
                    sacc[f][r] = p; tl[r] += p;
                }
            #pragma unroll
            for (int msk = 1; msk < 16; msk <<= 1)
                #pragma unroll
                for (int r = 0; r < 4; ++r) tl[r] += __shfl_xor(tl[r], msk, 64);
            #pragma unroll
            for (int r = 0; r < 4; ++r) lrow[r] = lrow[r]*corr[r] + tl[r];
            #pragma unroll
            for (int ct = 0; ct < 4; ++ct)
                #pragma unroll
                for (int r = 0; r < 4; ++r) oacc[ct][r] *= corr[r];
            // ---- P -> per-wave LDS (in-wave DS ordering; no cross-wave barrier)
            char* Pw = (char*)&Pls[w][0];
            #pragma unroll
            for (int f = 0; f < 8; ++f)
                #pragma unroll
                for (int r = 0; r < 4; ++r) {
                    int row = 4*lg + r, col = lr + 16*f;
                    *(__bf16*)(Pw + ((row*256 + col*2) ^ ((row&7)<<4))) = (__bf16)sacc[f][r];
                }
            // ---- O += P V  (4 d-tiles x 4 k-steps)
            const char* Vb = (const char*)Vls[cur];
            bf16x8 pa[4];
            #pragma unroll
            for (int ks = 0; ks < 4; ++ks)
                pa[ks] = *(const bf16x8*)(Pw + ((lr*256 + (lg*8+32*ks)*2) ^ ((lr&7)<<4)));
            #pragma unroll
            for (int ct = 0; ct < 4; ++ct) {
                int row = lr + 16*ct;
                int swz = (row & 7) << 4;
                #pragma unroll
                for (int ks = 0; ks < 4; ++ks) {
                    bf16x8 vf = *(const bf16x8*)(Vb + ((row*256 + (lg*8+32*ks)*2) ^ swz));
                    oacc[ct] = __builtin_amdgcn_mfma_f32_16x16x32_bf16(pa[ks], vf, oacc[ct], 0,0,0);
                }
            }
            if (more) { COMMIT(cur^1); __syncthreads(); }   // single barrier per tile
        }
        // ---- epilogue
        #pragma unroll
        for (int ct = 0; ct < 4; ++ct)
            #pragma unroll
            for (int r = 0; r < 4; ++r) {
                int q = q0 + 16*w + 4*lg + r;
                ao[(size_t)q*HDIM + h*64 + 16*ct + lr] = (__bf16)(oacc[ct][r] / lrow[r]);
            }
    }
#undef ISSUE
#undef COMMIT
}

// ---------------- Router (f32 exact) ----------------
__global__ __launch_bounds__(256)
void router_kernel(const float* __restrict__ x, const float* __restrict__ rw,
                   int* __restrict__ expi, float* __restrict__ expp) {
    int t = blockIdx.x, tid = threadIdx.x;
    __shared__ float red[256][8];
    float part[8] = {};
    const float* xr = x + (size_t)t*HDIM;
    for (int i = tid; i < HDIM; i += 256) {
        float xv = xr[i];
        const float* wp = rw + (size_t)i*NEXP;
        #pragma unroll
        for (int e2 = 0; e2 < 8; ++e2) part[e2] += xv * wp[e2];
    }
    #pragma unroll
    for (int e2 = 0; e2 < 8; ++e2) red[tid][e2] = part[e2];
    __syncthreads();
    for (int st = 128; st > 0; st >>= 1) {
        if (tid < st)
            #pragma unroll
            for (int e2 = 0; e2 < 8; ++e2) red[tid][e2] += red[tid+st][e2];
        __syncthreads();
    }
    if (tid == 0) {
        float lg[8];
        #pragma unroll
        for (int e2 = 0; e2 < 8; ++e2) lg[e2] = red[0][e2];
        int i0 = 0;
        for (int e2 = 1; e2 < 8; ++e2) if (lg[e2] > lg[i0]) i0 = e2;
        int i1 = -1;
        for (int e2 = 0; e2 < 8; ++e2) { if (e2 == i0) continue; if (i1 < 0 || lg[e2] > lg[i1]) i1 = e2; }
        float p1 = __expf(lg[i1] - lg[i0]);
        float inv = 1.f / (1.f + p1);
        expi[t*2]   = i0; expi[t*2+1] = i1;
        expp[t*2]   = inv; expp[t*2+1] = p1 * inv;
    }
}

// ---------------- Stable rank -> destination (single block, wave-scan) ----------------
__global__ __launch_bounds__(256)
void dst_fast_kernel(const int* __restrict__ expi, int* __restrict__ dst) {
    __shared__ int hist[256][9];
    const int tid = threadIdx.x;
    int ev[16];
    #pragma unroll
    for (int i = 0; i < 16; i += 4)
        *(int4*)(ev+i) = *(const int4*)(expi + tid*16 + i);
    int cnt[8] = {};
    #pragma unroll
    for (int i = 0; i < 16; ++i)
        #pragma unroll
        for (int e = 0; e < 8; ++e) cnt[e] += (ev[i] == e);
    #pragma unroll
    for (int e = 0; e < 8; ++e) hist[tid][e] = cnt[e];
    __syncthreads();
    const int w = tid >> 6, lane = tid & 63;
    #pragma unroll
    for (int rep = 0; rep < 2; ++rep) {
        int e = w + rep*4;
        int h0 = hist[4*lane+0][e], h1 = hist[4*lane+1][e],
            h2 = hist[4*lane+2][e], h3 = hist[4*lane+3][e];
        int s = h0+h1+h2+h3, inc = s;
        #pragma unroll
        for (int off = 1; off < 64; off <<= 1) {
            int v = __shfl_up(inc, off, 64);
            if (lane >= off) inc += v;
        }
        int excl = inc - s;
        hist[4*lane+0][e] = excl;
        hist[4*lane+1][e] = excl + h0;
        hist[4*lane+2][e] = excl + h0 + h1;
        hist[4*lane+3][e] = excl + h0 + h1 + h2;
    }
    __syncthreads();
    int run[8];
    #pragma unroll
    for (int e = 0; e < 8; ++e) run[e] = hist[tid][e];
    int out[16];
    #pragma unroll
    for (int i = 0; i < 16; ++i) {
        int e = ev[i], within = 0;
        #pragma unroll
        for (int e2 = 0; e2 < 8; ++e2)
            if (e == e2) { within = run[e2]; run[e2]++; }
        out[i] = (within < CAP) ? (e*CAP + within) : -1;
    }
    #pragma unroll
    for (int i = 0; i < 16; i += 4)
        *(int4*)(dst + tid*16 + i) = *(const int4*)(out+i);
}

// ---------------- Scatter (f32 x -> bf16 xt) ----------------
__global__ void scatter_kernel(const float* __restrict__ x, const int* __restrict__ dst,
                               __bf16* __restrict__ xt) {
    int s = blockIdx.x;
    int d = dst[s];
    if (d < 0) return;
    int t = s >> 1;
    int i = threadIdx.x;
    float4 f = ((const float4*)(x + (size_t)t*HDIM))[i];
    __bf16* dp = xt + (size_t)d*HDIM + i*4;
    dp[0]=(__bf16)f.x; dp[1]=(__bf16)f.y; dp[2]=(__bf16)f.z; dp[3]=(__bf16)f.w;
}

// ---------------- Combine ----------------
__global__ void combine_kernel(const float* __restrict__ h1, const float* __restrict__ fc2,
                               const int* __restrict__ dst, const float* __restrict__ expp,
                               float* __restrict__ out) {
    int t = blockIdx.x;
    int d0 = dst[t*2], d1 = dst[t*2+1];
    float p0 = expp[t*2], p1 = expp[t*2+1];
    for (int i = threadIdx.x; i < HDIM; i += 256) {
        float v = h1[(size_t)t*HDIM + i];
        if (d0 >= 0) v += p0 * fc2[(size_t)d0*HDIM + i];
        if (d1 >= 0) v += p1 * fc2[(size_t)d1*HDIM + i];
        out[(size_t)t*HDIM + i] = v;
    }
}

extern "C" void kernel_launch(void* const* d_in, const int* in_sizes, int n_in,
                              void* d_out, int out_size, void* d_ws, size_t ws_size,
                              hipStream_t stream) {
    const float* hidden = (const float*)d_in[0];
    const float* ln1w   = (const float*)d_in[1];
    const float* ln1b_  = (const float*)d_in[2];
    const float* ln2w   = (const float*)d_in[3];
    const float* ln2b_  = (const float*)d_in[4];
    const float* qkvW   = (const float*)d_in[5];
    const float* projW  = (const float*)d_in[6];
    const float* routW  = (const float*)d_in[7];
    const float* w1     = (const float*)d_in[8];
    const float* w2     = (const float*)d_in[9];
    float* out = (float*)d_out;

    char* base = (char*)d_ws;
    __bf16* w1t    = (__bf16*)(base);                 // [E][FDIM][HDIM]
    __bf16* w2t    = (__bf16*)(base + 33554432);      // [E][HDIM][FDIM]
    __bf16* ln1b   = (__bf16*)(base + 0);             // aliases w1t span; dead before transpose
    __bf16* qkvWb  = (__bf16*)(base + 4194304);
    __bf16* qkvb   = (__bf16*)(base + 7340032);
    __bf16* aob    = (__bf16*)(base + 13631488);
    __bf16* projWb = (__bf16*)(base + 17825792);
    char* B0 = base + 67108864;
    float*  h1   = (float*)(B0);
    __bf16* xtb  = (__bf16*)(B0 + 8388608);
    __bf16* fc1b = (__bf16*)(B0 + 18874368);
    float*  fc2  = (float*)(B0 + 39845888);
    float*  x2   = fc2;
    int*    expi = (int*)(B0 + 60817408);
    int*    dsts = (int*)(B0 + 60833792);
    float*  expp = (float*)(B0 + 60850176);

    ln_kernel<true><<<S_LEN, 256, 0, stream>>>(hidden, ln1w, ln1b_, ln1b);
    conv_bf16_kernel<<<(QKV_O*HDIM/8 + 255)/256, 256, 0, stream>>>(qkvW, qkvWb, QKV_O*HDIM/8);
    gemm_bf16_kernel<3><<<dim3(QKV_O/128, S_LEN/128, 1), 256, 0, stream>>>(
        ln1b, qkvWb, nullptr, qkvb, QKV_O, HDIM, 0, 0, 0);
    attn_mfma_kernel<<<dim3(16, NHEAD), 512, 0, stream>>>(qkvb, aob);
    conv_bf16_kernel<<<(HDIM*HDIM/8 + 255)/256, 256, 0, stream>>>(projW, projWb, HDIM*HDIM/8);
    gemm_bf16_kernel<1><<<dim3(HDIM/128, S_LEN/128, 1), 256, 0, stream>>>(
        aob, projWb, hidden, h1, HDIM, HDIM, 0, 0, 0);
    ln_kernel<false><<<S_LEN, 256, 0, stream>>>(h1, ln2w, ln2b_, x2);
    router_kernel<<<S_LEN, 256, 0, stream>>>(x2, routW, expi, expp);
    dst_fast_kernel<<<1, 256, 0, stream>>>(expi, dsts);
    hipMemsetAsync(xtb, 0, (size_t)TCAP * HDIM * sizeof(__bf16), stream);
    scatter_kernel<<<S_LEN*TOPK, 256, 0, stream>>>(x2, dsts, xtb);
    transp_conv_kernel<<<dim3(FDIM/32, HDIM/32, NEXP), 256, 0, stream>>>(w1, w1t, HDIM, FDIM);
    transp_conv_kernel<<<dim3(HDIM/32, FDIM/32, NEXP), 256, 0, stream>>>(w2, w2t, FDIM, HDIM);
    gemm_bf16_kernel<2><<<dim3(FDIM/128, CAP/128, NEXP), 256, 0, stream>>>(
        xtb, w1t, nullptr, fc1b, FDIM, HDIM,
        (long)CAP*HDIM, (long)FDIM*HDIM, (long)CAP*FDIM);
    gemm_bf16_kernel<0><<<dim3(HDIM/128, CAP/128, NEXP), 256, 0, stream>>>(
        fc1b, w2t, nullptr, fc2, HDIM, FDIM,
        (long)CAP*FDIM, (long)FDIM*HDIM, (long)CAP*HDIM);
    combine_kernel<<<S_LEN, 256, 0, stream>>>(h1, fc2, dsts, expp, out);
}